// Round 5
// baseline (310.978 us; speedup 1.0000x reference)
//
#include <hip/hip_runtime.h>

typedef __bf16 bf16x8 __attribute__((ext_vector_type(8)));
typedef float f32x4 __attribute__((ext_vector_type(4)));
typedef unsigned int u32x4 __attribute__((ext_vector_type(4)));
typedef unsigned int u32x2 __attribute__((ext_vector_type(2)));
typedef unsigned short u16;
typedef unsigned int u32;

// ---- constants for this problem ----
#define BSZ 2
#define TSEQ 2048
#define DMODEL 1024
#define NHEAD 16
#define DHEAD 64

// async global->LDS, 16B per lane, dest = wave-uniform base + lane*16
#define GLDS(gp, lp)                                                        \
  __builtin_amdgcn_global_load_lds(                                         \
      (const __attribute__((address_space(1))) void*)(gp),                  \
      (__attribute__((address_space(3))) void*)(lp), 16, 0, 0)

__device__ __forceinline__ u16 f2bf(float f) {
  u32 u = __builtin_bit_cast(u32, f);
  u32 r = (u + 0x7fffu + ((u >> 16) & 1u)) >> 16;   // RNE
  return (u16)r;
}
__device__ __forceinline__ float bf2f(u16 h) {
  return __builtin_bit_cast(float, (u32)h << 16);
}

// ---------------- fp32 -> bf16 convert (4 elems/thread) ----------------
__global__ void k_cvt(const float* __restrict__ in, u16* __restrict__ out, int n4) {
  int i = blockIdx.x * 256 + threadIdx.x;
  if (i >= n4) return;
  float4 v = ((const float4*)in)[i];
  ushort4 o;
  o.x = f2bf(v.x); o.y = f2bf(v.y); o.z = f2bf(v.z); o.w = f2bf(v.w);
  ((ushort4*)out)[i] = o;
}

// ------------- transpose + convert: in [K][N] f32 -> out [N][K] bf16 -------------
__global__ void k_transpose_cvt(const float* __restrict__ in, u16* __restrict__ out,
                                int K, int N) {
  __shared__ float tile[64][65];
  int n0 = blockIdx.x * 64, k0 = blockIdx.y * 64;
  int tx = threadIdx.x & 63, ty = threadIdx.x >> 6;
#pragma unroll
  for (int i = ty; i < 64; i += 4)
    tile[i][tx] = in[(size_t)(k0 + i) * N + n0 + tx];
  __syncthreads();
#pragma unroll
  for (int i = ty; i < 64; i += 4)
    out[(size_t)(n0 + i) * K + k0 + tx] = f2bf(tile[tx][i]);
}

// ---------------- RoPE cos/sin table: [T][32] each ----------------
__global__ void k_rope_table(float* __restrict__ cosT, float* __restrict__ sinT) {
  int idx = blockIdx.x * 256 + threadIdx.x;  // T*32
  int t = idx >> 5, f = idx & 31;
  float inv_freq = powf(10000.0f, -(float)(2 * f) / 64.0f);
  float ang = (float)t * inv_freq;
  float s, c;
  sincosf(ang, &s, &c);
  cosT[idx] = c;
  sinT[idx] = s;
}

// ---------------- GEMM: C[M][N] = A[M][K] * Bt[N][K]^T ----------------
// T3/T4 2-phase: double-buffered LDS, GLDS prefetch with counted vmcnt (never 0
// in the main loop) across raw s_barriers.
__device__ __forceinline__ void store_out(u16* C, size_t i, float v) { C[i] = f2bf(v); }
__device__ __forceinline__ void store_out(float* C, size_t i, float v) { C[i] = v; }

template <typename OutT>
__global__ __launch_bounds__(256) void k_gemm(const u16* __restrict__ A,
                                              const u16* __restrict__ Bt,
                                              OutT* __restrict__ C, int M, int N, int K) {
  __shared__ __align__(16) u16 a_lds[2][128][32];   // unpadded (GLDS requirement)
  __shared__ __align__(16) u16 b_lds[2][128][32];
  int m0 = blockIdx.y * 128, n0 = blockIdx.x * 128;
  int tid = threadIdx.x;
  int w = tid >> 6, l = tid & 63, lr = l & 15, lg = l >> 4;
  int wr = (w >> 1) * 64, wc = (w & 1) * 64;
  int grow = l >> 2;        // 0..15 row within 16-row chunk
  int gcol = (l & 3) * 8;   // k-chunk (8 bf16 = 16B)
  f32x4 acc[4][4] = {};

  const u16* a0 = A + (size_t)(m0 + w * 16 + grow) * K + gcol;
  const u16* a1 = A + (size_t)(m0 + (w + 4) * 16 + grow) * K + gcol;
  const u16* b0 = Bt + (size_t)(n0 + w * 16 + grow) * K + gcol;
  const u16* b1 = Bt + (size_t)(n0 + (w + 4) * 16 + grow) * K + gcol;

  int NT = K >> 5;
  // prologue: stage tile 0 into buf 0
  GLDS(a0, &a_lds[0][w * 16][0]);
  GLDS(a1, &a_lds[0][(w + 4) * 16][0]);
  GLDS(b0, &b_lds[0][w * 16][0]);
  GLDS(b1, &b_lds[0][(w + 4) * 16][0]);

  for (int t = 0; t < NT; ++t) {
    int p = t & 1;
    if (t + 1 < NT) {   // issue next-tile loads FIRST; they stay in flight
      int k0 = (t + 1) << 5;
      GLDS(a0 + k0, &a_lds[p ^ 1][w * 16][0]);
      GLDS(a1 + k0, &a_lds[p ^ 1][(w + 4) * 16][0]);
      GLDS(b0 + k0, &b_lds[p ^ 1][w * 16][0]);
      GLDS(b1 + k0, &b_lds[p ^ 1][(w + 4) * 16][0]);
      asm volatile("s_waitcnt vmcnt(4)" ::: "memory");  // oldest 4 (buf p) done
    } else {
      asm volatile("s_waitcnt vmcnt(0)" ::: "memory");
    }
    __builtin_amdgcn_s_barrier();          // all waves' buf-p loads landed
    __builtin_amdgcn_sched_barrier(0);     // no ds_read hoists above this
    bf16x8 af[4], bfv[4];
#pragma unroll
    for (int mt = 0; mt < 4; ++mt)
      af[mt] = __builtin_bit_cast(bf16x8, *(const u32x4*)&a_lds[p][wr + mt * 16 + lr][lg * 8]);
#pragma unroll
    for (int nt = 0; nt < 4; ++nt)
      bfv[nt] = __builtin_bit_cast(bf16x8, *(const u32x4*)&b_lds[p][wc + nt * 16 + lr][lg * 8]);
    __builtin_amdgcn_s_setprio(1);
#pragma unroll
    for (int mt = 0; mt < 4; ++mt)
#pragma unroll
      for (int nt = 0; nt < 4; ++nt)
        acc[mt][nt] = __builtin_amdgcn_mfma_f32_16x16x32_bf16(af[mt], bfv[nt], acc[mt][nt], 0, 0, 0);
    __builtin_amdgcn_s_setprio(0);
    __builtin_amdgcn_sched_barrier(0);
    __builtin_amdgcn_s_barrier();          // all waves done reading buf p
  }

#pragma unroll
  for (int mt = 0; mt < 4; ++mt)
#pragma unroll
    for (int nt = 0; nt < 4; ++nt)
#pragma unroll
      for (int r = 0; r < 4; ++r) {
        int row = m0 + wr + mt * 16 + lg * 4 + r;
        int col = n0 + wc + nt * 16 + lr;
        store_out(C, (size_t)row * N + col, acc[mt][nt][r]);
      }
}

// ---------------- RoPE apply + [B,T,3D] -> [B,H,T,DH] split ----------------
__global__ void k_rope_apply(const u16* __restrict__ qkv, const float* __restrict__ cosT,
                             const float* __restrict__ sinT, u16* __restrict__ Q,
                             u16* __restrict__ K, u16* __restrict__ V) {
  int idx = blockIdx.x * 256 + threadIdx.x;
  int d = idx & 63;
  int t = (idx >> 6) & 2047;
  int h = (idx >> 17) & 15;
  int b = idx >> 21;
  size_t row = (size_t)(b * TSEQ + t) * (3 * DMODEL);
  int cq = h * 64 + d;
  int cp = h * 64 + (d ^ 32);
  float q  = bf2f(qkv[row + cq]);
  float qp = bf2f(qkv[row + cp]);
  float k  = bf2f(qkv[row + DMODEL + cq]);
  float kp = bf2f(qkv[row + DMODEL + cp]);
  float v  = bf2f(qkv[row + 2 * DMODEL + cq]);
  int f = d & 31;
  float c = cosT[t * 32 + f], s = sinT[t * 32 + f];
  float sgn = (d < 32) ? -1.0f : 1.0f;
  float qr = (q * c + sgn * qp * s) * 0.125f;  // fold score scale into Q
  float kr = k * c + sgn * kp * s;
  Q[idx] = f2bf(qr);
  K[idx] = f2bf(kr);
  V[idx] = f2bf(v);
}

// ---------------- flash attention (causal), QBLK=64, KVBLK=128, 4 waves ----------------
__global__ __launch_bounds__(256) void k_flash(const u16* __restrict__ Qg, const u16* __restrict__ Kg,
                                               const u16* __restrict__ Vg, u16* __restrict__ O) {
  __shared__ __align__(16) u16 k_lds[128][72];   // 18.4 KB, padded: conflict-free b128 reads
  __shared__ __align__(16) u16 vsub[8192];       // 2 x (64x64 subtiled V), 16 KB
  __shared__ __align__(16) u16 p_lds[4][16][68]; // stride 34 dwords: conflict-free writes
  int xb = blockIdx.x;
  int qb = (xb & 1) ? (xb >> 1) : (31 - (xb >> 1));  // interleave heavy/light
  int bh = blockIdx.y;
  int b = bh >> 4, h = bh & 15;
  size_t hoff = (size_t)bh * TSEQ * DHEAD;
  int tid = threadIdx.x, w = tid >> 6, l = tid & 63, lr = l & 15, lg = l >> 4;

  // Q fragments (registers, whole block)
  int qrow = qb * 64 + w * 16 + lr;
  const u16* qp = Qg + hoff + (size_t)qrow * 64 + lg * 8;
  bf16x8 qf0 = __builtin_bit_cast(bf16x8, *(const u32x4*)qp);
  bf16x8 qf1 = __builtin_bit_cast(bf16x8, *(const u32x4*)(qp + 32));

  f32x4 acc[4] = {};
  float mrow[4] = {-1e30f, -1e30f, -1e30f, -1e30f};
  float lrow[4] = {0.f, 0.f, 0.f, 0.f};

  int srow = tid >> 3;        // 0..31
  int g8 = tid & 7;
  int sc8 = g8 * 8;
  u32 vtrbase = (u32)(uintptr_t)vsub + (u32)(lg * 1024 + lr * 8);

  const u16* kbase = Kg + hoff;
  const u16* vbase = Vg + hoff;
  u32x4 kreg[4], vreg[4];
#pragma unroll
  for (int p = 0; p < 4; ++p) {   // prologue: tile kvt=0 (128 rows)
    int r = srow + p * 32;
    kreg[p] = *(const u32x4*)(kbase + (size_t)r * 64 + sc8);
    vreg[p] = *(const u32x4*)(vbase + (size_t)r * 64 + sc8);
  }

  int nkv = (qb >> 1) + 1;
  for (int kvt = 0; kvt < nkv; ++kvt) {
    __syncthreads();   // previous tile fully consumed
#pragma unroll
    for (int p = 0; p < 4; ++p) {
      int r = srow + p * 32;
      *(u32x4*)&k_lds[r][sc8] = kreg[p];
      int rr = r & 63;
      int vo = (r >> 6) * 4096 + (rr >> 2) * 256 + (g8 >> 1) * 64 + (rr & 3) * 16 + (g8 & 1) * 8;
      *(u32x4*)&vsub[vo] = vreg[p];
    }
    __syncthreads();
    if (kvt + 1 < nkv) {   // T14: prefetch next tile; hides under compute
#pragma unroll
      for (int p = 0; p < 4; ++p) {
        int r = (kvt + 1) * 128 + srow + p * 32;
        kreg[p] = *(const u32x4*)(kbase + (size_t)r * 64 + sc8);
        vreg[p] = *(const u32x4*)(vbase + (size_t)r * 64 + sc8);
      }
    }

    // diagonal-tile handling
    int ng = 8, mstart = 8;
    if (kvt == (qb >> 1)) {
      if (qb & 1) { ng = 8; mstart = 4; }
      else        { ng = 4; mstart = 0; }
    }

    // S = (Q*scale) K^T  -- 16 x (ng*16) per wave
    f32x4 s[8];
    __builtin_amdgcn_s_setprio(1);
#pragma unroll
    for (int c = 0; c < 8; ++c) {
      if (c >= ng) break;
      const u16* kp2 = &k_lds[c * 16 + lr][lg * 8];
      bf16x8 kf0 = __builtin_bit_cast(bf16x8, *(const u32x4*)kp2);
      bf16x8 kf1 = __builtin_bit_cast(bf16x8, *(const u32x4*)(kp2 + 32));
      f32x4 z = {};
      z = __builtin_amdgcn_mfma_f32_16x16x32_bf16(qf0, kf0, z, 0, 0, 0);
      s[c] = __builtin_amdgcn_mfma_f32_16x16x32_bf16(qf1, kf1, z, 0, 0, 0);
    }
    __builtin_amdgcn_s_setprio(0);
    // causal mask within diagonal tile: col > row
    int rowin = (qb & 1) * 64 + w * 16 + lg * 4;
#pragma unroll
    for (int c = 0; c < 8; ++c) {
      if (c >= ng) break;
      if (c >= mstart) {
#pragma unroll
        for (int r = 0; r < 4; ++r)
          if (c * 16 + lr > rowin + r) s[c][r] = -1e30f;
      }
    }

    // online softmax over ng*16 cols (one pass per 128 cols)
    float rmax[4], rsum[4], alpha[4];
#pragma unroll
    for (int r = 0; r < 4; ++r) rmax[r] = s[0][r];
#pragma unroll
    for (int c = 1; c < 8; ++c) {
      if (c >= ng) break;
#pragma unroll
      for (int r = 0; r < 4; ++r) rmax[r] = fmaxf(rmax[r], s[c][r]);
    }
#pragma unroll
    for (int mset = 1; mset <= 8; mset <<= 1)
#pragma unroll
      for (int r = 0; r < 4; ++r)
        rmax[r] = fmaxf(rmax[r], __shfl_xor(rmax[r], mset, 64));
#pragma unroll
    for (int r = 0; r < 4; ++r) {
      float mn = fmaxf(mrow[r], rmax[r]);
      alpha[r] = __expf(mrow[r] - mn);
      mrow[r] = mn;
      rsum[r] = 0.0f;
    }
#pragma unroll
    for (int c = 0; c < 8; ++c) {
      if (c >= ng) break;
#pragma unroll
      for (int r = 0; r < 4; ++r) {
        float pe = __expf(s[c][r] - mrow[r]);
        s[c][r] = pe;
        rsum[r] += pe;
      }
    }
#pragma unroll
    for (int mset = 1; mset <= 8; mset <<= 1)
#pragma unroll
      for (int r = 0; r < 4; ++r)
        rsum[r] += __shfl_xor(rsum[r], mset, 64);
#pragma unroll
    for (int r = 0; r < 4; ++r)
      lrow[r] = lrow[r] * alpha[r] + rsum[r];
#pragma unroll
    for (int n = 0; n < 4; ++n)
#pragma unroll
      for (int r = 0; r < 4; ++r)
        acc[n][r] *= alpha[r];

    // PV per 64-row K/V half: P -> bf16 LDS (wave-local) -> A-frag; V via tr-reads
#pragma unroll
    for (int half = 0; half < 2; ++half) {
      if (half == 1 && ng == 4) break;
#pragma unroll
      for (int c = 0; c < 4; ++c)
#pragma unroll
        for (int r = 0; r < 4; ++r)
          p_lds[w][lg * 4 + r][c * 16 + lr] = f2bf(s[half * 4 + c][r]);
      bf16x8 pa0 = __builtin_bit_cast(bf16x8, *(const u32x4*)&p_lds[w][lr][lg * 8]);
      bf16x8 pa1 = __builtin_bit_cast(bf16x8, *(const u32x4*)&p_lds[w][lr][lg * 8 + 32]);
      u32 vb0 = vtrbase + (u32)(half * 8192);
#pragma unroll
      for (int nh = 0; nh < 2; ++nh) {
        u32x2 t[8];
#pragma unroll
        for (int n2 = 0; n2 < 2; ++n2) {
          int n = nh * 2 + n2;
#pragma unroll
          for (int hh = 0; hh < 2; ++hh) {
            u32 alo = vb0 + (u32)(hh * 512 + n * 128);
            u32 ahi = alo + 4096;
            asm volatile("ds_read_b64_tr_b16 %0, %1" : "=v"(t[n2 * 4 + hh]) : "v"(alo) : "memory");
            asm volatile("ds_read_b64_tr_b16 %0, %1" : "=v"(t[n2 * 4 + 2 + hh]) : "v"(ahi) : "memory");
          }
        }
        asm volatile("s_waitcnt lgkmcnt(0)" ::: "memory");
        __builtin_amdgcn_sched_barrier(0);
        __builtin_amdgcn_s_setprio(1);
#pragma unroll
        for (int n2 = 0; n2 < 2; ++n2) {
          int n = nh * 2 + n2;
          u32x4 vlo, vhi;
          vlo[0] = t[n2 * 4 + 0][0]; vlo[1] = t[n2 * 4 + 0][1];
          vlo[2] = t[n2 * 4 + 1][0]; vlo[3] = t[n2 * 4 + 1][1];
          vhi[0] = t[n2 * 4 + 2][0]; vhi[1] = t[n2 * 4 + 2][1];
          vhi[2] = t[n2 * 4 + 3][0]; vhi[3] = t[n2 * 4 + 3][1];
          acc[n] = __builtin_amdgcn_mfma_f32_16x16x32_bf16(pa0, __builtin_bit_cast(bf16x8, vlo), acc[n], 0, 0, 0);
          acc[n] = __builtin_amdgcn_mfma_f32_16x16x32_bf16(pa1, __builtin_bit_cast(bf16x8, vhi), acc[n], 0, 0, 0);
        }
        __builtin_amdgcn_s_setprio(0);
      }
    }
  }

  // epilogue: normalize, write [B,T,H*DH]
#pragma unroll
  for (int n = 0; n < 4; ++n)
#pragma unroll
    for (int r = 0; r < 4; ++r) {
      int t = qb * 64 + w * 16 + lg * 4 + r;
      int dd = n * 16 + lr;
      float ov = acc[n][r] / lrow[r];
      O[(size_t)(b * TSEQ + t) * DMODEL + h * 64 + dd] = f2bf(ov);
    }
}

extern "C" void kernel_launch(void* const* d_in, const int* in_sizes, int n_in,
                              void* d_out, int out_size, void* d_ws, size_t ws_size,
                              hipStream_t stream) {
  const float* x     = (const float*)d_in[0];  // [2,2048,1024]
  const float* w_qkv = (const float*)d_in[1];  // [1024,3072]
  const float* w_out = (const float*)d_in[2];  // [1024,1024]
  float* out = (float*)d_out;                  // [2,2048,1024]

  char* ws = (char*)d_ws;
  size_t off = 0;
  auto alloc = [&](size_t bytes) {
    char* p = ws + off;
    off += (bytes + 255) & ~(size_t)255;
    return p;
  };
  const size_t MT = (size_t)BSZ * TSEQ;  // 4096
  u16* xb    = (u16*)alloc(MT * DMODEL * 2);
  u16* wqkvT = (u16*)alloc((size_t)3 * DMODEL * DMODEL * 2);
  u16* woutT = (u16*)alloc((size_t)DMODEL * DMODEL * 2);
  u16* qkv   = (u16*)alloc(MT * 3 * DMODEL * 2);
  u16* Qh    = (u16*)alloc(MT * DMODEL * 2);
  u16* Kh    = (u16*)alloc(MT * DMODEL * 2);
  u16* Vh    = (u16*)alloc(MT * DMODEL * 2);
  u16* aout  = (u16*)alloc(MT * DMODEL * 2);
  float* cosT = (float*)alloc((size_t)TSEQ * 32 * 4);
  float* sinT = (float*)alloc((size_t)TSEQ * 32 * 4);
  if (ws_size < off) return;

  k_cvt<<<(MT * DMODEL / 4 + 255) / 256, 256, 0, stream>>>(x, xb, MT * DMODEL / 4);
  k_transpose_cvt<<<dim3(48, 16), 256, 0, stream>>>(w_qkv, wqkvT, DMODEL, 3 * DMODEL);
  k_transpose_cvt<<<dim3(16, 16), 256, 0, stream>>>(w_out, woutT, DMODEL, DMODEL);
  k_rope_table<<<(TSEQ * 32) / 256, 256, 0, stream>>>(cosT, sinT);
  k_gemm<u16><<<dim3(24, 32), 256, 0, stream>>>(xb, wqkvT, qkv, (int)MT, 3 * DMODEL, DMODEL);
  k_rope_apply<<<(int)(MT * DMODEL / 256), 256, 0, stream>>>(qkv, cosT, sinT, Qh, Kh, Vh);
  k_flash<<<dim3(TSEQ / 64, BSZ * NHEAD), 256, 0, stream>>>(Qh, Kh, Vh, aout);
  k_gemm<float><<<dim3(8, 32), 256, 0, stream>>>(aout, woutT, out, (int)MT, DMODEL, DMODEL);
}

// Round 6
// 231.924 us; speedup vs baseline: 1.3409x; 1.3409x over previous
//
#include <hip/hip_runtime.h>

typedef __bf16 bf16x8 __attribute__((ext_vector_type(8)));
typedef float f32x4 __attribute__((ext_vector_type(4)));
typedef unsigned int u32x4 __attribute__((ext_vector_type(4)));
typedef unsigned int u32x2 __attribute__((ext_vector_type(2)));
typedef unsigned short u16;
typedef unsigned int u32;

// ---- constants for this problem ----
#define BSZ 2
#define TSEQ 2048
#define DMODEL 1024
#define NHEAD 16
#define DHEAD 64

// async global->LDS, 16B per lane, dest = wave-uniform base + lane*16
#define GLDS(gp, lp)                                                        \
  __builtin_amdgcn_global_load_lds(                                         \
      (const __attribute__((address_space(1))) void*)(gp),                  \
      (__attribute__((address_space(3))) void*)(lp), 16, 0, 0)

// native cast -> compiler emits v_cvt_pk_bf16_f32 (RNE), pairs adjacent uses
__device__ __forceinline__ u16 f2bf(float f) {
  return __builtin_bit_cast(u16, (__bf16)f);
}
__device__ __forceinline__ float bf2f(u16 h) {
  return __builtin_bit_cast(float, (u32)h << 16);
}

// ---------------- fp32 -> bf16 convert (4 elems/thread) ----------------
__global__ void k_cvt(const float* __restrict__ in, u16* __restrict__ out, int n4) {
  int i = blockIdx.x * 256 + threadIdx.x;
  if (i >= n4) return;
  float4 v = ((const float4*)in)[i];
  ushort4 o;
  o.x = f2bf(v.x); o.y = f2bf(v.y); o.z = f2bf(v.z); o.w = f2bf(v.w);
  ((ushort4*)out)[i] = o;
}

// ------------- transpose + convert: in [K][N] f32 -> out [N][K] bf16 -------------
__global__ void k_transpose_cvt(const float* __restrict__ in, u16* __restrict__ out,
                                int K, int N) {
  __shared__ float tile[64][65];
  int n0 = blockIdx.x * 64, k0 = blockIdx.y * 64;
  int tx = threadIdx.x & 63, ty = threadIdx.x >> 6;
#pragma unroll
  for (int i = ty; i < 64; i += 4)
    tile[i][tx] = in[(size_t)(k0 + i) * N + n0 + tx];
  __syncthreads();
#pragma unroll
  for (int i = ty; i < 64; i += 4)
    out[(size_t)(n0 + i) * K + k0 + tx] = f2bf(tile[tx][i]);
}

// ---------------- RoPE cos/sin table: [T][32] each ----------------
__global__ void k_rope_table(float* __restrict__ cosT, float* __restrict__ sinT) {
  int idx = blockIdx.x * 256 + threadIdx.x;  // T*32
  int t = idx >> 5, f = idx & 31;
  float inv_freq = powf(10000.0f, -(float)(2 * f) / 64.0f);
  float ang = (float)t * inv_freq;
  float s, c;
  sincosf(ang, &s, &c);
  cosT[idx] = c;
  sinT[idx] = s;
}

// ---------------- GEMM: C[M][N] = A[M][K] * Bt[N][K]^T ----------------
// T3/T4 2-phase: double-buffered LDS, GLDS prefetch, counted vmcnt across raw barriers.
__device__ __forceinline__ void store_out(u16* C, size_t i, float v) { C[i] = f2bf(v); }
__device__ __forceinline__ void store_out(float* C, size_t i, float v) { C[i] = v; }

template <typename OutT>
__global__ __launch_bounds__(256) void k_gemm(const u16* __restrict__ A,
                                              const u16* __restrict__ Bt,
                                              OutT* __restrict__ C, int M, int N, int K) {
  __shared__ __align__(16) u16 a_lds[2][128][32];   // unpadded (GLDS requirement)
  __shared__ __align__(16) u16 b_lds[2][128][32];
  int m0 = blockIdx.y * 128, n0 = blockIdx.x * 128;
  int tid = threadIdx.x;
  int w = tid >> 6, l = tid & 63, lr = l & 15, lg = l >> 4;
  int wr = (w >> 1) * 64, wc = (w & 1) * 64;
  int grow = l >> 2;        // 0..15 row within 16-row chunk
  int gcol = (l & 3) * 8;   // k-chunk (8 bf16 = 16B)
  f32x4 acc[4][4] = {};

  const u16* a0 = A + (size_t)(m0 + w * 16 + grow) * K + gcol;
  const u16* a1 = A + (size_t)(m0 + (w + 4) * 16 + grow) * K + gcol;
  const u16* b0 = Bt + (size_t)(n0 + w * 16 + grow) * K + gcol;
  const u16* b1 = Bt + (size_t)(n0 + (w + 4) * 16 + grow) * K + gcol;

  int NT = K >> 5;
  GLDS(a0, &a_lds[0][w * 16][0]);
  GLDS(a1, &a_lds[0][(w + 4) * 16][0]);
  GLDS(b0, &b_lds[0][w * 16][0]);
  GLDS(b1, &b_lds[0][(w + 4) * 16][0]);

  for (int t = 0; t < NT; ++t) {
    int p = t & 1;
    if (t + 1 < NT) {   // issue next-tile loads FIRST; they stay in flight
      int k0 = (t + 1) << 5;
      GLDS(a0 + k0, &a_lds[p ^ 1][w * 16][0]);
      GLDS(a1 + k0, &a_lds[p ^ 1][(w + 4) * 16][0]);
      GLDS(b0 + k0, &b_lds[p ^ 1][w * 16][0]);
      GLDS(b1 + k0, &b_lds[p ^ 1][(w + 4) * 16][0]);
      asm volatile("s_waitcnt vmcnt(4)" ::: "memory");  // oldest 4 (buf p) done
    } else {
      asm volatile("s_waitcnt vmcnt(0)" ::: "memory");
    }
    __builtin_amdgcn_s_barrier();
    __builtin_amdgcn_sched_barrier(0);
    bf16x8 af[4], bfv[4];
#pragma unroll
    for (int mt = 0; mt < 4; ++mt)
      af[mt] = __builtin_bit_cast(bf16x8, *(const u32x4*)&a_lds[p][wr + mt * 16 + lr][lg * 8]);
#pragma unroll
    for (int nt = 0; nt < 4; ++nt)
      bfv[nt] = __builtin_bit_cast(bf16x8, *(const u32x4*)&b_lds[p][wc + nt * 16 + lr][lg * 8]);
    __builtin_amdgcn_s_setprio(1);
#pragma unroll
    for (int mt = 0; mt < 4; ++mt)
#pragma unroll
      for (int nt = 0; nt < 4; ++nt)
        acc[mt][nt] = __builtin_amdgcn_mfma_f32_16x16x32_bf16(af[mt], bfv[nt], acc[mt][nt], 0, 0, 0);
    __builtin_amdgcn_s_setprio(0);
    __builtin_amdgcn_sched_barrier(0);
    __builtin_amdgcn_s_barrier();
  }

#pragma unroll
  for (int mt = 0; mt < 4; ++mt)
#pragma unroll
    for (int nt = 0; nt < 4; ++nt)
#pragma unroll
      for (int r = 0; r < 4; ++r) {
        int row = m0 + wr + mt * 16 + lg * 4 + r;
        int col = n0 + wc + nt * 16 + lr;
        store_out(C, (size_t)row * N + col, acc[mt][nt][r]);
      }
}

// ---------------- RoPE apply + [B,T,3D] -> [B,H,T,DH] split ----------------
__global__ void k_rope_apply(const u16* __restrict__ qkv, const float* __restrict__ cosT,
                             const float* __restrict__ sinT, u16* __restrict__ Q,
                             u16* __restrict__ K, u16* __restrict__ V) {
  int idx = blockIdx.x * 256 + threadIdx.x;
  int d = idx & 63;
  int t = (idx >> 6) & 2047;
  int h = (idx >> 17) & 15;
  int b = idx >> 21;
  size_t row = (size_t)(b * TSEQ + t) * (3 * DMODEL);
  int cq = h * 64 + d;
  int cp = h * 64 + (d ^ 32);
  float q  = bf2f(qkv[row + cq]);
  float qp = bf2f(qkv[row + cp]);
  float k  = bf2f(qkv[row + DMODEL + cq]);
  float kp = bf2f(qkv[row + DMODEL + cp]);
  float v  = bf2f(qkv[row + 2 * DMODEL + cq]);
  int f = d & 31;
  float c = cosT[t * 32 + f], s = sinT[t * 32 + f];
  float sgn = (d < 32) ? -1.0f : 1.0f;
  float qr = (q * c + sgn * qp * s) * 0.125f;  // fold score scale into Q
  float kr = k * c + sgn * kp * s;
  Q[idx] = f2bf(qr);
  K[idx] = f2bf(kr);
  V[idx] = f2bf(v);
}

// ---------------- flash attention (causal), QBLK=64, KVBLK=64, 4 waves ----------------
// Work-paired: block p handles q-tiles (31-p) then (p) -> 33 KV-iters per block, no tail.
// V staged subtiled, consumed via ds_read_b64_tr_b16 (layout HW-verified in R4).
__global__ __launch_bounds__(256) void k_flash(const u16* __restrict__ Qg, const u16* __restrict__ Kg,
                                               const u16* __restrict__ Vg, u16* __restrict__ O) {
  __shared__ __align__(16) u16 k_lds[64][72];
  __shared__ __align__(16) u16 vsub[4096];       // 64x64 V tile, subtiled
  __shared__ __align__(16) u16 p_lds[4][16][68];
  int pairIdx = blockIdx.x;             // 0..15
  int bh = blockIdx.y;                  // b*16+h
  int b = bh >> 4, h = bh & 15;
  size_t hoff = (size_t)bh * TSEQ * DHEAD;
  int tid = threadIdx.x, w = tid >> 6, l = tid & 63, lr = l & 15, lg = l >> 4;

  int srow = tid >> 3;        // 0..31
  int g8 = tid & 7;
  int sc8 = g8 * 8;
  u32 vtr = (u32)(uintptr_t)vsub + (u32)(lg * 1024 + lr * 8);

  const u16* kbase = Kg + hoff;
  const u16* vbase = Vg + hoff;

  for (int sub = 0; sub < 2; ++sub) {
    int qb = sub == 0 ? (31 - pairIdx) : pairIdx;   // heavy first

    // Q fragments (registers for this q-tile)
    int qrow = qb * 64 + w * 16 + lr;
    const u16* qp = Qg + hoff + (size_t)qrow * 64 + lg * 8;
    bf16x8 qf0 = __builtin_bit_cast(bf16x8, *(const u32x4*)qp);
    bf16x8 qf1 = __builtin_bit_cast(bf16x8, *(const u32x4*)(qp + 32));

    f32x4 acc[4] = {};
    float mrow[4] = {-1e30f, -1e30f, -1e30f, -1e30f};
    float lrow[4] = {0.f, 0.f, 0.f, 0.f};

    u32x4 kreg[2], vreg[2];
#pragma unroll
    for (int p = 0; p < 2; ++p) {   // prologue: tile kv=0 into regs
      int r = srow + p * 32;
      kreg[p] = *(const u32x4*)(kbase + (size_t)r * 64 + sc8);
      vreg[p] = *(const u32x4*)(vbase + (size_t)r * 64 + sc8);
    }

    for (int kv = 0; kv <= qb; ++kv) {
      __syncthreads();   // previous tile fully consumed (also covers sub transition)
#pragma unroll
      for (int p = 0; p < 2; ++p) {
        int r = srow + p * 32;
        *(u32x4*)&k_lds[r][sc8] = kreg[p];
        int vo = ((r >> 2) * 4 + (g8 >> 1)) * 64 + (r & 3) * 16 + (g8 & 1) * 8;
        *(u32x4*)&vsub[vo] = vreg[p];
      }
      __syncthreads();
      if (kv < qb) {   // T14: prefetch next tile; latency hides under compute
#pragma unroll
        for (int p = 0; p < 2; ++p) {
          int r = (kv + 1) * 64 + srow + p * 32;
          kreg[p] = *(const u32x4*)(kbase + (size_t)r * 64 + sc8);
          vreg[p] = *(const u32x4*)(vbase + (size_t)r * 64 + sc8);
        }
      }

      // S = (Q*scale) K^T  -- 16x64 per wave
      f32x4 s[4];
      __builtin_amdgcn_s_setprio(1);
#pragma unroll
      for (int c = 0; c < 4; ++c) {
        const u16* kp2 = &k_lds[c * 16 + lr][lg * 8];
        bf16x8 kf0 = __builtin_bit_cast(bf16x8, *(const u32x4*)kp2);
        bf16x8 kf1 = __builtin_bit_cast(bf16x8, *(const u32x4*)(kp2 + 32));
        f32x4 z = {};
        z = __builtin_amdgcn_mfma_f32_16x16x32_bf16(qf0, kf0, z, 0, 0, 0);
        s[c] = __builtin_amdgcn_mfma_f32_16x16x32_bf16(qf1, kf1, z, 0, 0, 0);
      }
      __builtin_amdgcn_s_setprio(0);
      if (kv == qb) {  // diagonal block: causal mask (col > row)
#pragma unroll
        for (int c = 0; c < 4; ++c)
#pragma unroll
          for (int r = 0; r < 4; ++r)
            if (c * 16 + lr > w * 16 + lg * 4 + r) s[c][r] = -1e30f;
      }

      // online softmax (rows spread across 16-lane groups, 4 rows/lane)
      float rmax[4], rsum[4];
#pragma unroll
      for (int r = 0; r < 4; ++r)
        rmax[r] = fmaxf(fmaxf(s[0][r], s[1][r]), fmaxf(s[2][r], s[3][r]));
#pragma unroll
      for (int mset = 1; mset <= 8; mset <<= 1)
#pragma unroll
        for (int r = 0; r < 4; ++r)
          rmax[r] = fmaxf(rmax[r], __shfl_xor(rmax[r], mset, 64));
      // T13 defer-max: skip rescale when tile max within THR=8 of running max
      bool need = (rmax[0] > mrow[0] + 8.0f) | (rmax[1] > mrow[1] + 8.0f) |
                  (rmax[2] > mrow[2] + 8.0f) | (rmax[3] > mrow[3] + 8.0f);
      if (__any(need)) {
        float alpha[4];
#pragma unroll
        for (int r = 0; r < 4; ++r) {
          float mn = fmaxf(mrow[r], rmax[r]);
          alpha[r] = __expf(mrow[r] - mn);
          mrow[r] = mn;
          lrow[r] *= alpha[r];
        }
#pragma unroll
        for (int n = 0; n < 4; ++n)
#pragma unroll
          for (int r = 0; r < 4; ++r)
            acc[n][r] *= alpha[r];
      }
#pragma unroll
      for (int r = 0; r < 4; ++r) rsum[r] = 0.0f;
#pragma unroll
      for (int c = 0; c < 4; ++c)
#pragma unroll
        for (int r = 0; r < 4; ++r) {
          float pe = __expf(s[c][r] - mrow[r]);
          s[c][r] = pe;
          rsum[r] += pe;
        }
#pragma unroll
      for (int mset = 1; mset <= 8; mset <<= 1)
#pragma unroll
        for (int r = 0; r < 4; ++r)
          rsum[r] += __shfl_xor(rsum[r], mset, 64);
#pragma unroll
      for (int r = 0; r < 4; ++r)
        lrow[r] += rsum[r];

      // P (fp32, C-layout) -> bf16 via per-wave LDS round-trip
#pragma unroll
      for (int c = 0; c < 4; ++c)
#pragma unroll
        for (int r = 0; r < 4; ++r)
          p_lds[w][lg * 4 + r][c * 16 + lr] = f2bf(s[c][r]);
      bf16x8 pa0 = __builtin_bit_cast(bf16x8, *(const u32x4*)&p_lds[w][lr][lg * 8]);
      bf16x8 pa1 = __builtin_bit_cast(bf16x8, *(const u32x4*)&p_lds[w][lr][lg * 8 + 32]);

      // PV: B-fragments via hardware transpose reads, two n at a time
#pragma unroll
      for (int half = 0; half < 2; ++half) {
        u32x2 t[8];
#pragma unroll
        for (int n2 = 0; n2 < 2; ++n2) {
          int n = half * 2 + n2;
#pragma unroll
          for (int hh = 0; hh < 2; ++hh) {
            u32 alo = vtr + (u32)(hh * 512 + n * 128);
            u32 ahi = alo + 4096;
            asm volatile("ds_read_b64_tr_b16 %0, %1" : "=v"(t[n2 * 4 + hh]) : "v"(alo) : "memory");
            asm volatile("ds_read_b64_tr_b16 %0, %1" : "=v"(t[n2 * 4 + 2 + hh]) : "v"(ahi) : "memory");
          }
        }
        asm volatile("s_waitcnt lgkmcnt(0)" ::: "memory");
        __builtin_amdgcn_sched_barrier(0);
        __builtin_amdgcn_s_setprio(1);
#pragma unroll
        for (int n2 = 0; n2 < 2; ++n2) {
          int n = half * 2 + n2;
          u32x4 vlo, vhi;
          vlo[0] = t[n2 * 4 + 0][0]; vlo[1] = t[n2 * 4 + 0][1];
          vlo[2] = t[n2 * 4 + 1][0]; vlo[3] = t[n2 * 4 + 1][1];
          vhi[0] = t[n2 * 4 + 2][0]; vhi[1] = t[n2 * 4 + 2][1];
          vhi[2] = t[n2 * 4 + 3][0]; vhi[3] = t[n2 * 4 + 3][1];
          acc[n] = __builtin_amdgcn_mfma_f32_16x16x32_bf16(pa0, __builtin_bit_cast(bf16x8, vlo), acc[n], 0, 0, 0);
          acc[n] = __builtin_amdgcn_mfma_f32_16x16x32_bf16(pa1, __builtin_bit_cast(bf16x8, vhi), acc[n], 0, 0, 0);
        }
        __builtin_amdgcn_s_setprio(0);
      }
    }

    // epilogue: normalize, write [B,T,H*DH]
#pragma unroll
    for (int n = 0; n < 4; ++n)
#pragma unroll
      for (int r = 0; r < 4; ++r) {
        int t = qb * 64 + w * 16 + lg * 4 + r;
        int dd = n * 16 + lr;
        float ov = acc[n][r] / lrow[r];
        O[(size_t)(b * TSEQ + t) * DMODEL + h * 64 + dd] = f2bf(ov);
      }
  }
}

extern "C" void kernel_launch(void* const* d_in, const int* in_sizes, int n_in,
                              void* d_out, int out_size, void* d_ws, size_t ws_size,
                              hipStream_t stream) {
  const float* x     = (const float*)d_in[0];  // [2,2048,1024]
  const float* w_qkv = (const float*)d_in[1];  // [1024,3072]
  const float* w_out = (const float*)d_in[2];  // [1024,1024]
  float* out = (float*)d_out;                  // [2,2048,1024]

  char* ws = (char*)d_ws;
  size_t off = 0;
  auto alloc = [&](size_t bytes) {
    char* p = ws + off;
    off += (bytes + 255) & ~(size_t)255;
    return p;
  };
  const size_t MT = (size_t)BSZ * TSEQ;  // 4096
  u16* xb    = (u16*)alloc(MT * DMODEL * 2);
  u16* wqkvT = (u16*)alloc((size_t)3 * DMODEL * DMODEL * 2);
  u16* woutT = (u16*)alloc((size_t)DMODEL * DMODEL * 2);
  u16* qkv   = (u16*)alloc(MT * 3 * DMODEL * 2);
  u16* Qh    = (u16*)alloc(MT * DMODEL * 2);
  u16* Kh    = (u16*)alloc(MT * DMODEL * 2);
  u16* Vh    = (u16*)alloc(MT * DMODEL * 2);
  u16* aout  = (u16*)alloc(MT * DMODEL * 2);
  float* cosT = (float*)alloc((size_t)TSEQ * 32 * 4);
  float* sinT = (float*)alloc((size_t)TSEQ * 32 * 4);
  if (ws_size < off) return;

  k_cvt<<<(MT * DMODEL / 4 + 255) / 256, 256, 0, stream>>>(x, xb, MT * DMODEL / 4);
  k_transpose_cvt<<<dim3(48, 16), 256, 0, stream>>>(w_qkv, wqkvT, DMODEL, 3 * DMODEL);
  k_transpose_cvt<<<dim3(16, 16), 256, 0, stream>>>(w_out, woutT, DMODEL, DMODEL);
  k_rope_table<<<(TSEQ * 32) / 256, 256, 0, stream>>>(cosT, sinT);
  k_gemm<u16><<<dim3(24, 32), 256, 0, stream>>>(xb, wqkvT, qkv, (int)MT, 3 * DMODEL, DMODEL);
  k_rope_apply<<<(int)(MT * DMODEL / 256), 256, 0, stream>>>(qkv, cosT, sinT, Qh, Kh, Vh);
  k_flash<<<dim3(16, BSZ * NHEAD), 256, 0, stream>>>(Qh, Kh, Vh, aout);
  k_gemm<float><<<dim3(8, 32), 256, 0, stream>>>(aout, woutT, out, (int)MT, DMODEL, DMODEL);
}

// Round 7
// 225.424 us; speedup vs baseline: 1.3795x; 1.0288x over previous
//
#include <hip/hip_runtime.h>

typedef __bf16 bf16x8 __attribute__((ext_vector_type(8)));
typedef float f32x4 __attribute__((ext_vector_type(4)));
typedef unsigned int u32x4 __attribute__((ext_vector_type(4)));
typedef unsigned int u32x2 __attribute__((ext_vector_type(2)));
typedef unsigned short u16;
typedef unsigned int u32;

// ---- constants for this problem ----
#define BSZ 2
#define TSEQ 2048
#define DMODEL 1024
#define NHEAD 16
#define DHEAD 64

// async global->LDS, 16B per lane, dest = wave-uniform base + lane*16
#define GLDS(gp, lp)                                                        \
  __builtin_amdgcn_global_load_lds(                                         \
      (const __attribute__((address_space(1))) void*)(gp),                  \
      (__attribute__((address_space(3))) void*)(lp), 16, 0, 0)

// native cast -> compiler emits v_cvt_pk_bf16_f32 (RNE), pairs adjacent uses
__device__ __forceinline__ u16 f2bf(float f) {
  return __builtin_bit_cast(u16, (__bf16)f);
}
__device__ __forceinline__ float bf2f(u16 h) {
  return __builtin_bit_cast(float, (u32)h << 16);
}

// ---------------- fp32 -> bf16 convert (4 elems/thread) ----------------
__global__ void k_cvt(const float* __restrict__ in, u16* __restrict__ out, int n4) {
  int i = blockIdx.x * 256 + threadIdx.x;
  if (i >= n4) return;
  float4 v = ((const float4*)in)[i];
  ushort4 o;
  o.x = f2bf(v.x); o.y = f2bf(v.y); o.z = f2bf(v.z); o.w = f2bf(v.w);
  ((ushort4*)out)[i] = o;
}

// ------------- transpose + convert: in [K][N] f32 -> out [N][K] bf16 -------------
__global__ void k_transpose_cvt(const float* __restrict__ in, u16* __restrict__ out,
                                int K, int N) {
  __shared__ float tile[64][65];
  int n0 = blockIdx.x * 64, k0 = blockIdx.y * 64;
  int tx = threadIdx.x & 63, ty = threadIdx.x >> 6;
#pragma unroll
  for (int i = ty; i < 64; i += 4)
    tile[i][tx] = in[(size_t)(k0 + i) * N + n0 + tx];
  __syncthreads();
#pragma unroll
  for (int i = ty; i < 64; i += 4)
    out[(size_t)(n0 + i) * K + k0 + tx] = f2bf(tile[tx][i]);
}

// ---------------- RoPE cos/sin table: [T][32] each ----------------
__global__ void k_rope_table(float* __restrict__ cosT, float* __restrict__ sinT) {
  int idx = blockIdx.x * 256 + threadIdx.x;  // T*32
  int t = idx >> 5, f = idx & 31;
  float inv_freq = powf(10000.0f, -(float)(2 * f) / 64.0f);
  float ang = (float)t * inv_freq;
  float s, c;
  sincosf(ang, &s, &c);
  cosT[idx] = c;
  sinT[idx] = s;
}

// ---------------- GEMM2: C[M][N] = A[M][K] * Bt[N][K]^T, fp32 out ----------------
template <typename OutT>
__global__ __launch_bounds__(256) void k_gemm(const u16* __restrict__ A,
                                              const u16* __restrict__ Bt,
                                              OutT* __restrict__ C, int M, int N, int K) {
  __shared__ __align__(16) u16 a_lds[2][128][32];   // unpadded (GLDS requirement)
  __shared__ __align__(16) u16 b_lds[2][128][32];
  int m0 = blockIdx.y * 128, n0 = blockIdx.x * 128;
  int tid = threadIdx.x;
  int w = tid >> 6, l = tid & 63, lr = l & 15, lg = l >> 4;
  int wr = (w >> 1) * 64, wc = (w & 1) * 64;
  int grow = l >> 2;
  int gcol = (l & 3) * 8;
  f32x4 acc[4][4] = {};

  const u16* a0 = A + (size_t)(m0 + w * 16 + grow) * K + gcol;
  const u16* a1 = A + (size_t)(m0 + (w + 4) * 16 + grow) * K + gcol;
  const u16* b0 = Bt + (size_t)(n0 + w * 16 + grow) * K + gcol;
  const u16* b1 = Bt + (size_t)(n0 + (w + 4) * 16 + grow) * K + gcol;

  int NT = K >> 5;
  GLDS(a0, &a_lds[0][w * 16][0]);
  GLDS(a1, &a_lds[0][(w + 4) * 16][0]);
  GLDS(b0, &b_lds[0][w * 16][0]);
  GLDS(b1, &b_lds[0][(w + 4) * 16][0]);

  for (int t = 0; t < NT; ++t) {
    int p = t & 1;
    if (t + 1 < NT) {
      int k0 = (t + 1) << 5;
      GLDS(a0 + k0, &a_lds[p ^ 1][w * 16][0]);
      GLDS(a1 + k0, &a_lds[p ^ 1][(w + 4) * 16][0]);
      GLDS(b0 + k0, &b_lds[p ^ 1][w * 16][0]);
      GLDS(b1 + k0, &b_lds[p ^ 1][(w + 4) * 16][0]);
      asm volatile("s_waitcnt vmcnt(4)" ::: "memory");
    } else {
      asm volatile("s_waitcnt vmcnt(0)" ::: "memory");
    }
    __builtin_amdgcn_s_barrier();
    __builtin_amdgcn_sched_barrier(0);
    bf16x8 af[4], bfv[4];
#pragma unroll
    for (int mt = 0; mt < 4; ++mt)
      af[mt] = __builtin_bit_cast(bf16x8, *(const u32x4*)&a_lds[p][wr + mt * 16 + lr][lg * 8]);
#pragma unroll
    for (int nt = 0; nt < 4; ++nt)
      bfv[nt] = __builtin_bit_cast(bf16x8, *(const u32x4*)&b_lds[p][wc + nt * 16 + lr][lg * 8]);
    __builtin_amdgcn_s_setprio(1);
#pragma unroll
    for (int mt = 0; mt < 4; ++mt)
#pragma unroll
      for (int nt = 0; nt < 4; ++nt)
        acc[mt][nt] = __builtin_amdgcn_mfma_f32_16x16x32_bf16(af[mt], bfv[nt], acc[mt][nt], 0, 0, 0);
    __builtin_amdgcn_s_setprio(0);
    __builtin_amdgcn_sched_barrier(0);
    __builtin_amdgcn_s_barrier();
  }

#pragma unroll
  for (int mt = 0; mt < 4; ++mt)
#pragma unroll
    for (int nt = 0; nt < 4; ++nt)
#pragma unroll
      for (int r = 0; r < 4; ++r) {
        int row = m0 + wr + mt * 16 + lg * 4 + r;
        int col = n0 + wc + nt * 16 + lr;
        C[(size_t)row * N + col] = acc[mt][nt][r];
      }
}

// ---------------- GEMM1 fused: x @ w_qkv with RoPE+split epilogue ----------------
// Writes Q (scaled+rope), K (rope), V directly in [b*16+h][t][dh] layout.
// RoPE pairs (d, d^32) are in-register: acc[mt][0]<->acc[mt][2], acc[mt][1]<->acc[mt][3].
__global__ __launch_bounds__(256) void k_gemm_qkv(const u16* __restrict__ A,
                                                  const u16* __restrict__ Bt,
                                                  u16* __restrict__ Qh, u16* __restrict__ Kh,
                                                  u16* __restrict__ Vh,
                                                  const float* __restrict__ cosT,
                                                  const float* __restrict__ sinT) {
  const int M = BSZ * TSEQ, N = 3 * DMODEL, K = DMODEL;
  __shared__ __align__(16) u16 a_lds[2][128][32];
  __shared__ __align__(16) u16 b_lds[2][128][32];
  int m0 = blockIdx.y * 128, n0 = blockIdx.x * 128;
  int tid = threadIdx.x;
  int w = tid >> 6, l = tid & 63, lr = l & 15, lg = l >> 4;
  int wr = (w >> 1) * 64, wc = (w & 1) * 64;
  int grow = l >> 2;
  int gcol = (l & 3) * 8;
  f32x4 acc[4][4] = {};

  const u16* a0 = A + (size_t)(m0 + w * 16 + grow) * K + gcol;
  const u16* a1 = A + (size_t)(m0 + (w + 4) * 16 + grow) * K + gcol;
  const u16* b0 = Bt + (size_t)(n0 + w * 16 + grow) * K + gcol;
  const u16* b1 = Bt + (size_t)(n0 + (w + 4) * 16 + grow) * K + gcol;

  int NT = K >> 5;
  GLDS(a0, &a_lds[0][w * 16][0]);
  GLDS(a1, &a_lds[0][(w + 4) * 16][0]);
  GLDS(b0, &b_lds[0][w * 16][0]);
  GLDS(b1, &b_lds[0][(w + 4) * 16][0]);

  for (int t = 0; t < NT; ++t) {
    int p = t & 1;
    if (t + 1 < NT) {
      int k0 = (t + 1) << 5;
      GLDS(a0 + k0, &a_lds[p ^ 1][w * 16][0]);
      GLDS(a1 + k0, &a_lds[p ^ 1][(w + 4) * 16][0]);
      GLDS(b0 + k0, &b_lds[p ^ 1][w * 16][0]);
      GLDS(b1 + k0, &b_lds[p ^ 1][(w + 4) * 16][0]);
      asm volatile("s_waitcnt vmcnt(4)" ::: "memory");
    } else {
      asm volatile("s_waitcnt vmcnt(0)" ::: "memory");
    }
    __builtin_amdgcn_s_barrier();
    __builtin_amdgcn_sched_barrier(0);
    bf16x8 af[4], bfv[4];
#pragma unroll
    for (int mt = 0; mt < 4; ++mt)
      af[mt] = __builtin_bit_cast(bf16x8, *(const u32x4*)&a_lds[p][wr + mt * 16 + lr][lg * 8]);
#pragma unroll
    for (int nt = 0; nt < 4; ++nt)
      bfv[nt] = __builtin_bit_cast(bf16x8, *(const u32x4*)&b_lds[p][wc + nt * 16 + lr][lg * 8]);
    __builtin_amdgcn_s_setprio(1);
#pragma unroll
    for (int mt = 0; mt < 4; ++mt)
#pragma unroll
      for (int nt = 0; nt < 4; ++nt)
        acc[mt][nt] = __builtin_amdgcn_mfma_f32_16x16x32_bf16(af[mt], bfv[nt], acc[mt][nt], 0, 0, 0);
    __builtin_amdgcn_s_setprio(0);
    __builtin_amdgcn_sched_barrier(0);
    __builtin_amdgcn_s_barrier();
  }

  // ---- fused epilogue: RoPE + head-split ----
  int sec = n0 >> 10;                         // 0=Q 1=K 2=V (uniform per block)
  int hcol = ((n0 + wc) & 1023) >> 6;         // head index (uniform per wave)
  u16* outp = (sec == 0) ? Qh : (sec == 1) ? Kh : Vh;
  float qscale = (sec == 0) ? 0.125f : 1.0f;
#pragma unroll
  for (int mt = 0; mt < 4; ++mt)
#pragma unroll
    for (int r = 0; r < 4; ++r) {
      int row = m0 + wr + mt * 16 + lg * 4 + r;
      int b = row >> 11, tt = row & 2047;
      size_t obase = ((size_t)((b * 16 + hcol) * 2048 + tt)) * 64;
      if (sec == 2) {
#pragma unroll
        for (int nt = 0; nt < 4; ++nt)
          outp[obase + nt * 16 + lr] = f2bf(acc[mt][nt][r]);
      } else {
        float c0 = cosT[tt * 32 + lr],      s0 = sinT[tt * 32 + lr];
        float c1 = cosT[tt * 32 + 16 + lr], s1 = sinT[tt * 32 + 16 + lr];
        float v0 = acc[mt][0][r], v1 = acc[mt][1][r];
        float v2 = acc[mt][2][r], v3 = acc[mt][3][r];
        outp[obase + lr]      = f2bf((v0 * c0 - v2 * s0) * qscale);  // d = lr
        outp[obase + 16 + lr] = f2bf((v1 * c1 - v3 * s1) * qscale);  // d = 16+lr
        outp[obase + 32 + lr] = f2bf((v2 * c0 + v0 * s0) * qscale);  // d = 32+lr
        outp[obase + 48 + lr] = f2bf((v3 * c1 + v1 * s1) * qscale);  // d = 48+lr
      }
    }
}

// ---------------- flash attention (causal), QBLK=64, KVBLK=64, 4 waves ----------------
// Work-paired (33 iters/block), K/V double-buffered in LDS -> ONE barrier per iter.
__global__ __launch_bounds__(256) void k_flash(const u16* __restrict__ Qg, const u16* __restrict__ Kg,
                                               const u16* __restrict__ Vg, u16* __restrict__ O) {
  __shared__ __align__(16) u16 k_lds[2][64][72];
  __shared__ __align__(16) u16 vsub[2][4096];
  __shared__ __align__(16) u16 p_lds[4][16][68];
  int pairIdx = blockIdx.x;             // 0..15
  int bh = blockIdx.y;                  // b*16+h
  int b = bh >> 4, h = bh & 15;
  size_t hoff = (size_t)bh * TSEQ * DHEAD;
  int tid = threadIdx.x, w = tid >> 6, l = tid & 63, lr = l & 15, lg = l >> 4;

  int srow = tid >> 3;        // 0..31
  int g8 = tid & 7;
  int sc8 = g8 * 8;
  u32 vtr0 = (u32)(uintptr_t)vsub + (u32)(lg * 1024 + lr * 8);

  const u16* kbase = Kg + hoff;
  const u16* vbase = Vg + hoff;

  for (int sub = 0; sub < 2; ++sub) {
    int qb = sub == 0 ? (31 - pairIdx) : pairIdx;   // heavy first

    int qrow = qb * 64 + w * 16 + lr;
    const u16* qp = Qg + hoff + (size_t)qrow * 64 + lg * 8;
    bf16x8 qf0 = __builtin_bit_cast(bf16x8, *(const u32x4*)qp);
    bf16x8 qf1 = __builtin_bit_cast(bf16x8, *(const u32x4*)(qp + 32));

    f32x4 acc[4] = {};
    float mrow[4] = {-1e30f, -1e30f, -1e30f, -1e30f};
    float lrow[4] = {0.f, 0.f, 0.f, 0.f};

    u32x4 kreg[2], vreg[2];
#pragma unroll
    for (int p = 0; p < 2; ++p) {   // prologue: tile kv=0 into regs
      int r = srow + p * 32;
      kreg[p] = *(const u32x4*)(kbase + (size_t)r * 64 + sc8);
      vreg[p] = *(const u32x4*)(vbase + (size_t)r * 64 + sc8);
    }
    __syncthreads();   // buffers from previous sub fully consumed

    for (int kv = 0; kv <= qb; ++kv) {
      int cur = kv & 1;
#pragma unroll
      for (int p = 0; p < 2; ++p) {
        int r = srow + p * 32;
        *(u32x4*)&k_lds[cur][r][sc8] = kreg[p];
        int vo = ((r >> 2) * 4 + (g8 >> 1)) * 64 + (r & 3) * 16 + (g8 & 1) * 8;
        *(u32x4*)&vsub[cur][vo] = vreg[p];
      }
      __syncthreads();   // single barrier: buf[cur] ready; buf[cur^1] free
      if (kv < qb) {     // T14: prefetch next tile; latency hides under compute
#pragma unroll
        for (int p = 0; p < 2; ++p) {
          int r = (kv + 1) * 64 + srow + p * 32;
          kreg[p] = *(const u32x4*)(kbase + (size_t)r * 64 + sc8);
          vreg[p] = *(const u32x4*)(vbase + (size_t)r * 64 + sc8);
        }
      }

      // S = (Q*scale) K^T  -- 16x64 per wave
      f32x4 s[4];
      __builtin_amdgcn_s_setprio(1);
#pragma unroll
      for (int c = 0; c < 4; ++c) {
        const u16* kp2 = &k_lds[cur][c * 16 + lr][lg * 8];
        bf16x8 kf0 = __builtin_bit_cast(bf16x8, *(const u32x4*)kp2);
        bf16x8 kf1 = __builtin_bit_cast(bf16x8, *(const u32x4*)(kp2 + 32));
        f32x4 z = {};
        z = __builtin_amdgcn_mfma_f32_16x16x32_bf16(qf0, kf0, z, 0, 0, 0);
        s[c] = __builtin_amdgcn_mfma_f32_16x16x32_bf16(qf1, kf1, z, 0, 0, 0);
      }
      __builtin_amdgcn_s_setprio(0);
      if (kv == qb) {  // diagonal block: causal mask (col > row)
#pragma unroll
        for (int c = 0; c < 4; ++c)
#pragma unroll
          for (int r = 0; r < 4; ++r)
            if (c * 16 + lr > w * 16 + lg * 4 + r) s[c][r] = -1e30f;
      }

      // online softmax (rows spread across 16-lane groups, 4 rows/lane)
      float rmax[4], rsum[4];
#pragma unroll
      for (int r = 0; r < 4; ++r)
        rmax[r] = fmaxf(fmaxf(s[0][r], s[1][r]), fmaxf(s[2][r], s[3][r]));
#pragma unroll
      for (int mset = 1; mset <= 8; mset <<= 1)
#pragma unroll
        for (int r = 0; r < 4; ++r)
          rmax[r] = fmaxf(rmax[r], __shfl_xor(rmax[r], mset, 64));
      // T13 defer-max: skip rescale when tile max within THR=8 of running max
      bool need = (rmax[0] > mrow[0] + 8.0f) | (rmax[1] > mrow[1] + 8.0f) |
                  (rmax[2] > mrow[2] + 8.0f) | (rmax[3] > mrow[3] + 8.0f);
      if (__any(need)) {
        float alpha[4];
#pragma unroll
        for (int r = 0; r < 4; ++r) {
          float mn = fmaxf(mrow[r], rmax[r]);
          alpha[r] = __expf(mrow[r] - mn);
          mrow[r] = mn;
          lrow[r] *= alpha[r];
        }
#pragma unroll
        for (int n = 0; n < 4; ++n)
#pragma unroll
          for (int r = 0; r < 4; ++r)
            acc[n][r] *= alpha[r];
      }
#pragma unroll
      for (int r = 0; r < 4; ++r) rsum[r] = 0.0f;
#pragma unroll
      for (int c = 0; c < 4; ++c)
#pragma unroll
        for (int r = 0; r < 4; ++r) {
          float pe = __expf(s[c][r] - mrow[r]);
          s[c][r] = pe;
          rsum[r] += pe;
        }
#pragma unroll
      for (int mset = 1; mset <= 8; mset <<= 1)
#pragma unroll
        for (int r = 0; r < 4; ++r)
          rsum[r] += __shfl_xor(rsum[r], mset, 64);
#pragma unroll
      for (int r = 0; r < 4; ++r)
        lrow[r] += rsum[r];

      // P (fp32, C-layout) -> bf16 via per-wave LDS round-trip
#pragma unroll
      for (int c = 0; c < 4; ++c)
#pragma unroll
        for (int r = 0; r < 4; ++r)
          p_lds[w][lg * 4 + r][c * 16 + lr] = f2bf(s[c][r]);
      bf16x8 pa0 = __builtin_bit_cast(bf16x8, *(const u32x4*)&p_lds[w][lr][lg * 8]);
      bf16x8 pa1 = __builtin_bit_cast(bf16x8, *(const u32x4*)&p_lds[w][lr][lg * 8 + 32]);

      // PV: B-fragments via hardware transpose reads, two n at a time
      u32 vtr = vtr0 + (u32)(cur * 8192);
#pragma unroll
      for (int half = 0; half < 2; ++half) {
        u32x2 t[8];
#pragma unroll
        for (int n2 = 0; n2 < 2; ++n2) {
          int n = half * 2 + n2;
#pragma unroll
          for (int hh = 0; hh < 2; ++hh) {
            u32 alo = vtr + (u32)(hh * 512 + n * 128);
            u32 ahi = alo + 4096;
            asm volatile("ds_read_b64_tr_b16 %0, %1" : "=v"(t[n2 * 4 + hh]) : "v"(alo) : "memory");
            asm volatile("ds_read_b64_tr_b16 %0, %1" : "=v"(t[n2 * 4 + 2 + hh]) : "v"(ahi) : "memory");
          }
        }
        asm volatile("s_waitcnt lgkmcnt(0)" ::: "memory");
        __builtin_amdgcn_sched_barrier(0);
        __builtin_amdgcn_s_setprio(1);
#pragma unroll
        for (int n2 = 0; n2 < 2; ++n2) {
          int n = half * 2 + n2;
          u32x4 vlo, vhi;
          vlo[0] = t[n2 * 4 + 0][0]; vlo[1] = t[n2 * 4 + 0][1];
          vlo[2] = t[n2 * 4 + 1][0]; vlo[3] = t[n2 * 4 + 1][1];
          vhi[0] = t[n2 * 4 + 2][0]; vhi[1] = t[n2 * 4 + 2][1];
          vhi[2] = t[n2 * 4 + 3][0]; vhi[3] = t[n2 * 4 + 3][1];
          acc[n] = __builtin_amdgcn_mfma_f32_16x16x32_bf16(pa0, __builtin_bit_cast(bf16x8, vlo), acc[n], 0, 0, 0);
          acc[n] = __builtin_amdgcn_mfma_f32_16x16x32_bf16(pa1, __builtin_bit_cast(bf16x8, vhi), acc[n], 0, 0, 0);
        }
        __builtin_amdgcn_s_setprio(0);
      }
    }

    // epilogue: normalize, write [B,T,H*DH]
#pragma unroll
    for (int n = 0; n < 4; ++n)
#pragma unroll
      for (int r = 0; r < 4; ++r) {
        int t = qb * 64 + w * 16 + lg * 4 + r;
        int dd = n * 16 + lr;
        float ov = acc[n][r] / lrow[r];
        O[(size_t)(b * TSEQ + t) * DMODEL + h * 64 + dd] = f2bf(ov);
      }
  }
}

extern "C" void kernel_launch(void* const* d_in, const int* in_sizes, int n_in,
                              void* d_out, int out_size, void* d_ws, size_t ws_size,
                              hipStream_t stream) {
  const float* x     = (const float*)d_in[0];  // [2,2048,1024]
  const float* w_qkv = (const float*)d_in[1];  // [1024,3072]
  const float* w_out = (const float*)d_in[2];  // [1024,1024]
  float* out = (float*)d_out;                  // [2,2048,1024]

  char* ws = (char*)d_ws;
  size_t off = 0;
  auto alloc = [&](size_t bytes) {
    char* p = ws + off;
    off += (bytes + 255) & ~(size_t)255;
    return p;
  };
  const size_t MT = (size_t)BSZ * TSEQ;  // 4096
  u16* xb    = (u16*)alloc(MT * DMODEL * 2);
  u16* wqkvT = (u16*)alloc((size_t)3 * DMODEL * DMODEL * 2);
  u16* woutT = (u16*)alloc((size_t)DMODEL * DMODEL * 2);
  u16* Qh    = (u16*)alloc(MT * DMODEL * 2);
  u16* Kh    = (u16*)alloc(MT * DMODEL * 2);
  u16* Vh    = (u16*)alloc(MT * DMODEL * 2);
  u16* aout  = (u16*)alloc(MT * DMODEL * 2);
  float* cosT = (float*)alloc((size_t)TSEQ * 32 * 4);
  float* sinT = (float*)alloc((size_t)TSEQ * 32 * 4);
  if (ws_size < off) return;

  k_cvt<<<(MT * DMODEL / 4 + 255) / 256, 256, 0, stream>>>(x, xb, MT * DMODEL / 4);
  k_transpose_cvt<<<dim3(48, 16), 256, 0, stream>>>(w_qkv, wqkvT, DMODEL, 3 * DMODEL);
  k_transpose_cvt<<<dim3(16, 16), 256, 0, stream>>>(w_out, woutT, DMODEL, DMODEL);
  k_rope_table<<<(TSEQ * 32) / 256, 256, 0, stream>>>(cosT, sinT);
  k_gemm_qkv<<<dim3(24, 32), 256, 0, stream>>>(xb, wqkvT, Qh, Kh, Vh, cosT, sinT);
  k_flash<<<dim3(16, BSZ * NHEAD), 256, 0, stream>>>(Qh, Kh, Vh, aout);
  k_gemm<float><<<dim3(8, 32), 256, 0, stream>>>(aout, woutT, out, (int)MT, DMODEL, DMODEL);
}

// Round 8
// 218.164 us; speedup vs baseline: 1.4254x; 1.0333x over previous
//
#include <hip/hip_runtime.h>

typedef __bf16 bf16x8 __attribute__((ext_vector_type(8)));
typedef float f32x4 __attribute__((ext_vector_type(4)));
typedef unsigned int u32x4 __attribute__((ext_vector_type(4)));
typedef unsigned int u32x2 __attribute__((ext_vector_type(2)));
typedef unsigned short u16;
typedef unsigned int u32;

// ---- constants for this problem ----
#define BSZ 2
#define TSEQ 2048
#define DMODEL 1024
#define NHEAD 16
#define DHEAD 64

// async global->LDS, 16B per lane, dest = wave-uniform base + lane*16
#define GLDS(gp, lp)                                                        \
  __builtin_amdgcn_global_load_lds(                                         \
      (const __attribute__((address_space(1))) void*)(gp),                  \
      (__attribute__((address_space(3))) void*)(lp), 16, 0, 0)

// hardware transpose read with compile-time byte offset
#define TRR(dst, base, OFF)                                                 \
  asm volatile("ds_read_b64_tr_b16 %0, %1 offset:" OFF                     \
               : "=v"(dst) : "v"(base) : "memory")

// native cast -> compiler emits v_cvt_pk_bf16_f32 (RNE), pairs adjacent uses
__device__ __forceinline__ u16 f2bf(float f) {
  return __builtin_bit_cast(u16, (__bf16)f);
}
__device__ __forceinline__ float bf2f(u16 h) {
  return __builtin_bit_cast(float, (u32)h << 16);
}

// ---------------- fp32 -> bf16 convert (4 elems/thread) ----------------
__global__ void k_cvt(const float* __restrict__ in, u16* __restrict__ out, int n4) {
  int i = blockIdx.x * 256 + threadIdx.x;
  if (i >= n4) return;
  float4 v = ((const float4*)in)[i];
  ushort4 o;
  o.x = f2bf(v.x); o.y = f2bf(v.y); o.z = f2bf(v.z); o.w = f2bf(v.w);
  ((ushort4*)out)[i] = o;
}

// ------------- transpose + convert: in [K][N] f32 -> out [N][K] bf16 -------------
__global__ void k_transpose_cvt(const float* __restrict__ in, u16* __restrict__ out,
                                int K, int N) {
  __shared__ float tile[64][65];
  int n0 = blockIdx.x * 64, k0 = blockIdx.y * 64;
  int tx = threadIdx.x & 63, ty = threadIdx.x >> 6;
#pragma unroll
  for (int i = ty; i < 64; i += 4)
    tile[i][tx] = in[(size_t)(k0 + i) * N + n0 + tx];
  __syncthreads();
#pragma unroll
  for (int i = ty; i < 64; i += 4)
    out[(size_t)(n0 + i) * K + k0 + tx] = f2bf(tile[tx][i]);
}

// ---------------- RoPE cos/sin table: [T][32] each ----------------
__global__ void k_rope_table(float* __restrict__ cosT, float* __restrict__ sinT) {
  int idx = blockIdx.x * 256 + threadIdx.x;  // T*32
  int t = idx >> 5, f = idx & 31;
  float inv_freq = powf(10000.0f, -(float)(2 * f) / 64.0f);
  float ang = (float)t * inv_freq;
  float s, c;
  sincosf(ang, &s, &c);
  cosT[idx] = c;
  sinT[idx] = s;
}

// ---------------- GEMM2: C[M][N] = A[M][K] * Bt[N][K]^T, fp32 out ----------------
template <typename OutT>
__global__ __launch_bounds__(256) void k_gemm(const u16* __restrict__ A,
                                              const u16* __restrict__ Bt,
                                              OutT* __restrict__ C, int M, int N, int K) {
  __shared__ __align__(16) u16 a_lds[2][128][32];   // unpadded (GLDS requirement)
  __shared__ __align__(16) u16 b_lds[2][128][32];
  int m0 = blockIdx.y * 128, n0 = blockIdx.x * 128;
  int tid = threadIdx.x;
  int w = tid >> 6, l = tid & 63, lr = l & 15, lg = l >> 4;
  int wr = (w >> 1) * 64, wc = (w & 1) * 64;
  int grow = l >> 2;
  int gcol = (l & 3) * 8;
  f32x4 acc[4][4] = {};

  const u16* a0 = A + (size_t)(m0 + w * 16 + grow) * K + gcol;
  const u16* a1 = A + (size_t)(m0 + (w + 4) * 16 + grow) * K + gcol;
  const u16* b0 = Bt + (size_t)(n0 + w * 16 + grow) * K + gcol;
  const u16* b1 = Bt + (size_t)(n0 + (w + 4) * 16 + grow) * K + gcol;

  int NT = K >> 5;
  GLDS(a0, &a_lds[0][w * 16][0]);
  GLDS(a1, &a_lds[0][(w + 4) * 16][0]);
  GLDS(b0, &b_lds[0][w * 16][0]);
  GLDS(b1, &b_lds[0][(w + 4) * 16][0]);

  for (int t = 0; t < NT; ++t) {
    int p = t & 1;
    if (t + 1 < NT) {
      int k0 = (t + 1) << 5;
      GLDS(a0 + k0, &a_lds[p ^ 1][w * 16][0]);
      GLDS(a1 + k0, &a_lds[p ^ 1][(w + 4) * 16][0]);
      GLDS(b0 + k0, &b_lds[p ^ 1][w * 16][0]);
      GLDS(b1 + k0, &b_lds[p ^ 1][(w + 4) * 16][0]);
      asm volatile("s_waitcnt vmcnt(4)" ::: "memory");
    } else {
      asm volatile("s_waitcnt vmcnt(0)" ::: "memory");
    }
    __builtin_amdgcn_s_barrier();
    __builtin_amdgcn_sched_barrier(0);
    bf16x8 af[4], bfv[4];
#pragma unroll
    for (int mt = 0; mt < 4; ++mt)
      af[mt] = __builtin_bit_cast(bf16x8, *(const u32x4*)&a_lds[p][wr + mt * 16 + lr][lg * 8]);
#pragma unroll
    for (int nt = 0; nt < 4; ++nt)
      bfv[nt] = __builtin_bit_cast(bf16x8, *(const u32x4*)&b_lds[p][wc + nt * 16 + lr][lg * 8]);
    __builtin_amdgcn_s_setprio(1);
#pragma unroll
    for (int mt = 0; mt < 4; ++mt)
#pragma unroll
      for (int nt = 0; nt < 4; ++nt)
        acc[mt][nt] = __builtin_amdgcn_mfma_f32_16x16x32_bf16(af[mt], bfv[nt], acc[mt][nt], 0, 0, 0);
    __builtin_amdgcn_s_setprio(0);
    __builtin_amdgcn_sched_barrier(0);
    __builtin_amdgcn_s_barrier();
  }

#pragma unroll
  for (int mt = 0; mt < 4; ++mt)
#pragma unroll
    for (int nt = 0; nt < 4; ++nt)
#pragma unroll
      for (int r = 0; r < 4; ++r) {
        int row = m0 + wr + mt * 16 + lg * 4 + r;
        int col = n0 + wc + nt * 16 + lr;
        C[(size_t)row * N + col] = acc[mt][nt][r];
      }
}

// ---------------- GEMM1 fused: x @ w_qkv with RoPE+split epilogue ----------------
__global__ __launch_bounds__(256) void k_gemm_qkv(const u16* __restrict__ A,
                                                  const u16* __restrict__ Bt,
                                                  u16* __restrict__ Qh, u16* __restrict__ Kh,
                                                  u16* __restrict__ Vh,
                                                  const float* __restrict__ cosT,
                                                  const float* __restrict__ sinT) {
  const int M = BSZ * TSEQ, N = 3 * DMODEL, K = DMODEL;
  __shared__ __align__(16) u16 a_lds[2][128][32];
  __shared__ __align__(16) u16 b_lds[2][128][32];
  int m0 = blockIdx.y * 128, n0 = blockIdx.x * 128;
  int tid = threadIdx.x;
  int w = tid >> 6, l = tid & 63, lr = l & 15, lg = l >> 4;
  int wr = (w >> 1) * 64, wc = (w & 1) * 64;
  int grow = l >> 2;
  int gcol = (l & 3) * 8;
  f32x4 acc[4][4] = {};

  const u16* a0 = A + (size_t)(m0 + w * 16 + grow) * K + gcol;
  const u16* a1 = A + (size_t)(m0 + (w + 4) * 16 + grow) * K + gcol;
  const u16* b0 = Bt + (size_t)(n0 + w * 16 + grow) * K + gcol;
  const u16* b1 = Bt + (size_t)(n0 + (w + 4) * 16 + grow) * K + gcol;

  int NT = K >> 5;
  GLDS(a0, &a_lds[0][w * 16][0]);
  GLDS(a1, &a_lds[0][(w + 4) * 16][0]);
  GLDS(b0, &b_lds[0][w * 16][0]);
  GLDS(b1, &b_lds[0][(w + 4) * 16][0]);

  for (int t = 0; t < NT; ++t) {
    int p = t & 1;
    if (t + 1 < NT) {
      int k0 = (t + 1) << 5;
      GLDS(a0 + k0, &a_lds[p ^ 1][w * 16][0]);
      GLDS(a1 + k0, &a_lds[p ^ 1][(w + 4) * 16][0]);
      GLDS(b0 + k0, &b_lds[p ^ 1][w * 16][0]);
      GLDS(b1 + k0, &b_lds[p ^ 1][(w + 4) * 16][0]);
      asm volatile("s_waitcnt vmcnt(4)" ::: "memory");
    } else {
      asm volatile("s_waitcnt vmcnt(0)" ::: "memory");
    }
    __builtin_amdgcn_s_barrier();
    __builtin_amdgcn_sched_barrier(0);
    bf16x8 af[4], bfv[4];
#pragma unroll
    for (int mt = 0; mt < 4; ++mt)
      af[mt] = __builtin_bit_cast(bf16x8, *(const u32x4*)&a_lds[p][wr + mt * 16 + lr][lg * 8]);
#pragma unroll
    for (int nt = 0; nt < 4; ++nt)
      bfv[nt] = __builtin_bit_cast(bf16x8, *(const u32x4*)&b_lds[p][wc + nt * 16 + lr][lg * 8]);
    __builtin_amdgcn_s_setprio(1);
#pragma unroll
    for (int mt = 0; mt < 4; ++mt)
#pragma unroll
      for (int nt = 0; nt < 4; ++nt)
        acc[mt][nt] = __builtin_amdgcn_mfma_f32_16x16x32_bf16(af[mt], bfv[nt], acc[mt][nt], 0, 0, 0);
    __builtin_amdgcn_s_setprio(0);
    __builtin_amdgcn_sched_barrier(0);
    __builtin_amdgcn_s_barrier();
  }

  // ---- fused epilogue: RoPE + head-split ----
  int sec = n0 >> 10;                         // 0=Q 1=K 2=V (uniform per block)
  int hcol = ((n0 + wc) & 1023) >> 6;         // head index (uniform per wave)
  u16* outp = (sec == 0) ? Qh : (sec == 1) ? Kh : Vh;
  float qscale = (sec == 0) ? 0.125f : 1.0f;
#pragma unroll
  for (int mt = 0; mt < 4; ++mt)
#pragma unroll
    for (int r = 0; r < 4; ++r) {
      int row = m0 + wr + mt * 16 + lg * 4 + r;
      int b = row >> 11, tt = row & 2047;
      size_t obase = ((size_t)((b * 16 + hcol) * 2048 + tt)) * 64;
      if (sec == 2) {
#pragma unroll
        for (int nt = 0; nt < 4; ++nt)
          outp[obase + nt * 16 + lr] = f2bf(acc[mt][nt][r]);
      } else {
        float c0 = cosT[tt * 32 + lr],      s0 = sinT[tt * 32 + lr];
        float c1 = cosT[tt * 32 + 16 + lr], s1 = sinT[tt * 32 + 16 + lr];
        float v0 = acc[mt][0][r], v1 = acc[mt][1][r];
        float v2 = acc[mt][2][r], v3 = acc[mt][3][r];
        outp[obase + lr]      = f2bf((v0 * c0 - v2 * s0) * qscale);  // d = lr
        outp[obase + 16 + lr] = f2bf((v1 * c1 - v3 * s1) * qscale);  // d = 16+lr
        outp[obase + 32 + lr] = f2bf((v2 * c0 + v0 * s0) * qscale);  // d = 32+lr
        outp[obase + 48 + lr] = f2bf((v3 * c1 + v1 * s1) * qscale);  // d = 48+lr
      }
    }
}

// ---------------- flash attention (causal), QBLK=64, KVBLK=64, 4 waves ----------------
// Work-paired (33 iters/block), K/V double-buffered in LDS, one barrier/iter.
// This round: lane-partial lrow (no per-iter rsum shuffle reduce) + tr_read
// immediate offsets (no per-iter address adds).
__global__ __launch_bounds__(256) void k_flash(const u16* __restrict__ Qg, const u16* __restrict__ Kg,
                                               const u16* __restrict__ Vg, u16* __restrict__ O) {
  __shared__ __align__(16) u16 k_lds[2][64][72];
  __shared__ __align__(16) u16 vsub[2][4096];
  __shared__ __align__(16) u16 p_lds[4][16][68];
  int pairIdx = blockIdx.x;             // 0..15
  int bh = blockIdx.y;                  // b*16+h
  int b = bh >> 4, h = bh & 15;
  size_t hoff = (size_t)bh * TSEQ * DHEAD;
  int tid = threadIdx.x, w = tid >> 6, l = tid & 63, lr = l & 15, lg = l >> 4;

  int srow = tid >> 3;        // 0..31
  int g8 = tid & 7;
  int sc8 = g8 * 8;
  u32 vtr0 = (u32)(uintptr_t)vsub + (u32)(lg * 1024 + lr * 8);

  const u16* kbase = Kg + hoff;
  const u16* vbase = Vg + hoff;

  for (int sub = 0; sub < 2; ++sub) {
    int qb = sub == 0 ? (31 - pairIdx) : pairIdx;   // heavy first

    int qrow = qb * 64 + w * 16 + lr;
    const u16* qp = Qg + hoff + (size_t)qrow * 64 + lg * 8;
    bf16x8 qf0 = __builtin_bit_cast(bf16x8, *(const u32x4*)qp);
    bf16x8 qf1 = __builtin_bit_cast(bf16x8, *(const u32x4*)(qp + 32));

    f32x4 acc[4] = {};
    float mrow[4] = {-1e30f, -1e30f, -1e30f, -1e30f};
    float lrow[4] = {0.f, 0.f, 0.f, 0.f};   // LANE-PARTIAL: reduced in epilogue

    u32x4 kreg[2], vreg[2];
#pragma unroll
    for (int p = 0; p < 2; ++p) {   // prologue: tile kv=0 into regs
      int r = srow + p * 32;
      kreg[p] = *(const u32x4*)(kbase + (size_t)r * 64 + sc8);
      vreg[p] = *(const u32x4*)(vbase + (size_t)r * 64 + sc8);
    }
    __syncthreads();   // buffers from previous sub fully consumed

    for (int kv = 0; kv <= qb; ++kv) {
      int cur = kv & 1;
#pragma unroll
      for (int p = 0; p < 2; ++p) {
        int r = srow + p * 32;
        *(u32x4*)&k_lds[cur][r][sc8] = kreg[p];
        int vo = ((r >> 2) * 4 + (g8 >> 1)) * 64 + (r & 3) * 16 + (g8 & 1) * 8;
        *(u32x4*)&vsub[cur][vo] = vreg[p];
      }
      __syncthreads();   // single barrier: buf[cur] ready; buf[cur^1] free
      if (kv < qb) {     // prefetch next tile; latency hides under compute
#pragma unroll
        for (int p = 0; p < 2; ++p) {
          int r = (kv + 1) * 64 + srow + p * 32;
          kreg[p] = *(const u32x4*)(kbase + (size_t)r * 64 + sc8);
          vreg[p] = *(const u32x4*)(vbase + (size_t)r * 64 + sc8);
        }
      }

      // S = (Q*scale) K^T  -- 16x64 per wave
      f32x4 s[4];
      __builtin_amdgcn_s_setprio(1);
#pragma unroll
      for (int c = 0; c < 4; ++c) {
        const u16* kp2 = &k_lds[cur][c * 16 + lr][lg * 8];
        bf16x8 kf0 = __builtin_bit_cast(bf16x8, *(const u32x4*)kp2);
        bf16x8 kf1 = __builtin_bit_cast(bf16x8, *(const u32x4*)(kp2 + 32));
        f32x4 z = {};
        z = __builtin_amdgcn_mfma_f32_16x16x32_bf16(qf0, kf0, z, 0, 0, 0);
        s[c] = __builtin_amdgcn_mfma_f32_16x16x32_bf16(qf1, kf1, z, 0, 0, 0);
      }
      __builtin_amdgcn_s_setprio(0);
      if (kv == qb) {  // diagonal block: causal mask (col > row)
#pragma unroll
        for (int c = 0; c < 4; ++c)
#pragma unroll
          for (int r = 0; r < 4; ++r)
            if (c * 16 + lr > w * 16 + lg * 4 + r) s[c][r] = -1e30f;
      }

      // online softmax; row state (mrow) row-uniform, lrow lane-partial
      float rmax[4];
#pragma unroll
      for (int r = 0; r < 4; ++r)
        rmax[r] = fmaxf(fmaxf(s[0][r], s[1][r]), fmaxf(s[2][r], s[3][r]));
#pragma unroll
      for (int mset = 1; mset <= 8; mset <<= 1)
#pragma unroll
        for (int r = 0; r < 4; ++r)
          rmax[r] = fmaxf(rmax[r], __shfl_xor(rmax[r], mset, 64));
      // T13 defer-max: skip rescale when tile max within THR=8 of running max
      bool need = (rmax[0] > mrow[0] + 8.0f) | (rmax[1] > mrow[1] + 8.0f) |
                  (rmax[2] > mrow[2] + 8.0f) | (rmax[3] > mrow[3] + 8.0f);
      if (__any(need)) {
        float alpha[4];
#pragma unroll
        for (int r = 0; r < 4; ++r) {
          float mn = fmaxf(mrow[r], rmax[r]);
          alpha[r] = __expf(mrow[r] - mn);   // row-uniform -> partial lrow scaling OK
          mrow[r] = mn;
          lrow[r] *= alpha[r];
        }
#pragma unroll
        for (int n = 0; n < 4; ++n)
#pragma unroll
          for (int r = 0; r < 4; ++r)
            acc[n][r] *= alpha[r];
      }
#pragma unroll
      for (int c = 0; c < 4; ++c)
#pragma unroll
        for (int r = 0; r < 4; ++r) {
          float pe = __expf(s[c][r] - mrow[r]);
          s[c][r] = pe;
          lrow[r] += pe;   // lane-partial accumulate; no cross-lane reduce here
        }

      // P (fp32, C-layout) -> bf16 via per-wave LDS round-trip
#pragma unroll
      for (int c = 0; c < 4; ++c)
#pragma unroll
        for (int r = 0; r < 4; ++r)
          p_lds[w][lg * 4 + r][c * 16 + lr] = f2bf(s[c][r]);
      bf16x8 pa0 = __builtin_bit_cast(bf16x8, *(const u32x4*)&p_lds[w][lr][lg * 8]);
      bf16x8 pa1 = __builtin_bit_cast(bf16x8, *(const u32x4*)&p_lds[w][lr][lg * 8 + 32]);

      // PV: B-fragments via hardware transpose reads (immediate offsets)
      u32 vtr = vtr0 + (u32)(cur * 8192);
      {
        u32x2 t[8];
        TRR(t[0], vtr, "0");    TRR(t[1], vtr, "512");
        TRR(t[2], vtr, "4096"); TRR(t[3], vtr, "4608");
        TRR(t[4], vtr, "128");  TRR(t[5], vtr, "640");
        TRR(t[6], vtr, "4224"); TRR(t[7], vtr, "4736");
        asm volatile("s_waitcnt lgkmcnt(0)" ::: "memory");
        __builtin_amdgcn_sched_barrier(0);
        __builtin_amdgcn_s_setprio(1);
#pragma unroll
        for (int n2 = 0; n2 < 2; ++n2) {
          u32x4 vlo, vhi;
          vlo[0] = t[n2 * 4 + 0][0]; vlo[1] = t[n2 * 4 + 0][1];
          vlo[2] = t[n2 * 4 + 1][0]; vlo[3] = t[n2 * 4 + 1][1];
          vhi[0] = t[n2 * 4 + 2][0]; vhi[1] = t[n2 * 4 + 2][1];
          vhi[2] = t[n2 * 4 + 3][0]; vhi[3] = t[n2 * 4 + 3][1];
          acc[n2] = __builtin_amdgcn_mfma_f32_16x16x32_bf16(pa0, __builtin_bit_cast(bf16x8, vlo), acc[n2], 0, 0, 0);
          acc[n2] = __builtin_amdgcn_mfma_f32_16x16x32_bf16(pa1, __builtin_bit_cast(bf16x8, vhi), acc[n2], 0, 0, 0);
        }
        __builtin_amdgcn_s_setprio(0);
      }
      {
        u32x2 t[8];
        TRR(t[0], vtr, "256");  TRR(t[1], vtr, "768");
        TRR(t[2], vtr, "4352"); TRR(t[3], vtr, "4864");
        TRR(t[4], vtr, "384");  TRR(t[5], vtr, "896");
        TRR(t[6], vtr, "4480"); TRR(t[7], vtr, "4992");
        asm volatile("s_waitcnt lgkmcnt(0)" ::: "memory");
        __builtin_amdgcn_sched_barrier(0);
        __builtin_amdgcn_s_setprio(1);
#pragma unroll
        for (int n2 = 0; n2 < 2; ++n2) {
          int n = 2 + n2;
          u32x4 vlo, vhi;
          vlo[0] = t[n2 * 4 + 0][0]; vlo[1] = t[n2 * 4 + 0][1];
          vlo[2] = t[n2 * 4 + 1][0]; vlo[3] = t[n2 * 4 + 1][1];
          vhi[0] = t[n2 * 4 + 2][0]; vhi[1] = t[n2 * 4 + 2][1];
          vhi[2] = t[n2 * 4 + 3][0]; vhi[3] = t[n2 * 4 + 3][1];
          acc[n] = __builtin_amdgcn_mfma_f32_16x16x32_bf16(pa0, __builtin_bit_cast(bf16x8, vlo), acc[n], 0, 0, 0);
          acc[n] = __builtin_amdgcn_mfma_f32_16x16x32_bf16(pa1, __builtin_bit_cast(bf16x8, vhi), acc[n], 0, 0, 0);
        }
        __builtin_amdgcn_s_setprio(0);
      }
    }

    // epilogue: reduce lane-partial lrow across the 16-lane col groups, normalize
#pragma unroll
    for (int mset = 1; mset <= 8; mset <<= 1)
#pragma unroll
      for (int r = 0; r < 4; ++r)
        lrow[r] += __shfl_xor(lrow[r], mset, 64);
#pragma unroll
    for (int n = 0; n < 4; ++n)
#pragma unroll
      for (int r = 0; r < 4; ++r) {
        int t = qb * 64 + w * 16 + lg * 4 + r;
        int dd = n * 16 + lr;
        float ov = acc[n][r] / lrow[r];
        O[(size_t)(b * TSEQ + t) * DMODEL + h * 64 + dd] = f2bf(ov);
      }
  }
}

extern "C" void kernel_launch(void* const* d_in, const int* in_sizes, int n_in,
                              void* d_out, int out_size, void* d_ws, size_t ws_size,
                              hipStream_t stream) {
  const float* x     = (const float*)d_in[0];  // [2,2048,1024]
  const float* w_qkv = (const float*)d_in[1];  // [1024,3072]
  const float* w_out = (const float*)d_in[2];  // [1024,1024]
  float* out = (float*)d_out;                  // [2,2048,1024]

  char* ws = (char*)d_ws;
  size_t off = 0;
  auto alloc = [&](size_t bytes) {
    char* p = ws + off;
    off += (bytes + 255) & ~(size_t)255;
    return p;
  };
  const size_t MT = (size_t)BSZ * TSEQ;  // 4096
  u16* xb    = (u16*)alloc(MT * DMODEL * 2);
  u16* wqkvT = (u16*)alloc((size_t)3 * DMODEL * DMODEL * 2);
  u16* woutT = (u16*)alloc((size_t)DMODEL * DMODEL * 2);
  u16* Qh    = (u16*)alloc(MT * DMODEL * 2);
  u16* Kh    = (u16*)alloc(MT * DMODEL * 2);
  u16* Vh    = (u16*)alloc(MT * DMODEL * 2);
  u16* aout  = (u16*)alloc(MT * DMODEL * 2);
  float* cosT = (float*)alloc((size_t)TSEQ * 32 * 4);
  float* sinT = (float*)alloc((size_t)TSEQ * 32 * 4);
  if (ws_size < off) return;

  k_cvt<<<(MT * DMODEL / 4 + 255) / 256, 256, 0, stream>>>(x, xb, MT * DMODEL / 4);
  k_transpose_cvt<<<dim3(48, 16), 256, 0, stream>>>(w_qkv, wqkvT, DMODEL, 3 * DMODEL);
  k_transpose_cvt<<<dim3(16, 16), 256, 0, stream>>>(w_out, woutT, DMODEL, DMODEL);
  k_rope_table<<<(TSEQ * 32) / 256, 256, 0, stream>>>(cosT, sinT);
  k_gemm_qkv<<<dim3(24, 32), 256, 0, stream>>>(xb, wqkvT, Qh, Kh, Vh, cosT, sinT);
  k_flash<<<dim3(16, BSZ * NHEAD), 256, 0, stream>>>(Qh, Kh, Vh, aout);
  k_gemm<float><<<dim3(8, 32), 256, 0, stream>>>(aout, woutT, out, (int)MT, DMODEL, DMODEL);
}

// Round 9
// 202.361 us; speedup vs baseline: 1.5367x; 1.0781x over previous
//
#include <hip/hip_runtime.h>

typedef __bf16 bf16x8 __attribute__((ext_vector_type(8)));
typedef float f32x4 __attribute__((ext_vector_type(4)));
typedef unsigned int u32x4 __attribute__((ext_vector_type(4)));
typedef unsigned int u32x2 __attribute__((ext_vector_type(2)));
typedef unsigned short u16;
typedef unsigned int u32;

#define BSZ 2
#define TSEQ 2048
#define DMODEL 1024
#define NHEAD 16
#define DHEAD 64

#define GLDS(gp, lp)                                                        \
  __builtin_amdgcn_global_load_lds(                                         \
      (const __attribute__((address_space(1))) void*)(gp),                  \
      (__attribute__((address_space(3))) void*)(lp), 16, 0, 0)

#define TRR(dst, base, OFF)                                                 \
  asm volatile("ds_read_b64_tr_b16 %0, %1 offset:" OFF                     \
               : "=v"(dst) : "v"(base) : "memory")

__device__ __forceinline__ u16 f2bf(float f) {
  return __builtin_bit_cast(u16, (__bf16)f);
}
__device__ __forceinline__ u32 pack2bf(float lo, float hi) {
  return (u32)f2bf(lo) | ((u32)f2bf(hi) << 16);
}
__device__ __forceinline__ float bf2f(u16 h) {
  return __builtin_bit_cast(float, (u32)h << 16);
}

// ---------- fused pre-pass: cvt x | transpose wqkv | transpose wout | rope table ----------
__global__ void k_prep(const float* __restrict__ x, u16* __restrict__ xb,
                       const float* __restrict__ wqkv, u16* __restrict__ wqkvT,
                       const float* __restrict__ wout, u16* __restrict__ woutT,
                       float* __restrict__ cosT, float* __restrict__ sinT) {
  __shared__ float tile[64][65];
  int blk = blockIdx.x, tid = threadIdx.x;
  if (blk < 2048) {                       // cvt x -> bf16, 8 elems/thread
    int i = blk * 256 + tid;
    const float4* f4 = (const float4*)x;
    float4 v0 = f4[i * 2], v1 = f4[i * 2 + 1];
    u32x4 o;
    o[0] = pack2bf(v0.x, v0.y); o[1] = pack2bf(v0.z, v0.w);
    o[2] = pack2bf(v1.x, v1.y); o[3] = pack2bf(v1.z, v1.w);
    ((u32x4*)xb)[i] = o;
  } else if (blk < 2816) {                // transpose wqkv [1024][3072] -> [3072][1024]
    int idx = blk - 2048;
    int n0 = (idx % 48) * 64, k0 = (idx / 48) * 64;
    int tx = tid & 63, ty = tid >> 6;
#pragma unroll
    for (int i = ty; i < 64; i += 4)
      tile[i][tx] = wqkv[(size_t)(k0 + i) * 3072 + n0 + tx];
    __syncthreads();
#pragma unroll
    for (int i = ty; i < 64; i += 4)
      wqkvT[(size_t)(n0 + i) * 1024 + k0 + tx] = f2bf(tile[tx][i]);
  } else if (blk < 3072) {                // transpose wout [1024][1024]
    int idx = blk - 2816;
    int n0 = (idx % 16) * 64, k0 = (idx / 16) * 64;
    int tx = tid & 63, ty = tid >> 6;
#pragma unroll
    for (int i = ty; i < 64; i += 4)
      tile[i][tx] = wout[(size_t)(k0 + i) * 1024 + n0 + tx];
    __syncthreads();
#pragma unroll
    for (int i = ty; i < 64; i += 4)
      woutT[(size_t)(n0 + i) * 1024 + k0 + tx] = f2bf(tile[tx][i]);
  } else {                                // rope table [2048][32]
    int idx = (blk - 3072) * 256 + tid;
    int t = idx >> 5, f = idx & 31;
    float inv_freq = powf(10000.0f, -(float)(2 * f) / 64.0f);
    float ang = (float)t * inv_freq;
    float s, c;
    sincosf(ang, &s, &c);
    cosT[idx] = c;
    sinT[idx] = s;
  }
}

// ---------------- GEMM1 fused: x @ w_qkv with RoPE+split epilogue ----------------
__global__ __launch_bounds__(256) void k_gemm_qkv(const u16* __restrict__ A,
                                                  const u16* __restrict__ Bt,
                                                  u16* __restrict__ Qh, u16* __restrict__ Kh,
                                                  u16* __restrict__ Vh,
                                                  const float* __restrict__ cosT,
                                                  const float* __restrict__ sinT) {
  const int K = DMODEL;
  __shared__ __align__(16) u16 a_lds[2][128][32];
  __shared__ __align__(16) u16 b_lds[2][128][32];
  int m0 = blockIdx.y * 128, n0 = blockIdx.x * 128;
  int tid = threadIdx.x;
  int w = tid >> 6, l = tid & 63, lr = l & 15, lg = l >> 4;
  int wr = (w >> 1) * 64, wc = (w & 1) * 64;
  int grow = l >> 2;
  int gcol = (l & 3) * 8;
  f32x4 acc[4][4] = {};

  const u16* a0 = A + (size_t)(m0 + w * 16 + grow) * K + gcol;
  const u16* a1 = A + (size_t)(m0 + (w + 4) * 16 + grow) * K + gcol;
  const u16* b0 = Bt + (size_t)(n0 + w * 16 + grow) * K + gcol;
  const u16* b1 = Bt + (size_t)(n0 + (w + 4) * 16 + grow) * K + gcol;

  int NT = K >> 5;
  GLDS(a0, &a_lds[0][w * 16][0]);
  GLDS(a1, &a_lds[0][(w + 4) * 16][0]);
  GLDS(b0, &b_lds[0][w * 16][0]);
  GLDS(b1, &b_lds[0][(w + 4) * 16][0]);

  for (int t = 0; t < NT; ++t) {
    int p = t & 1;
    if (t + 1 < NT) {
      int k0 = (t + 1) << 5;
      GLDS(a0 + k0, &a_lds[p ^ 1][w * 16][0]);
      GLDS(a1 + k0, &a_lds[p ^ 1][(w + 4) * 16][0]);
      GLDS(b0 + k0, &b_lds[p ^ 1][w * 16][0]);
      GLDS(b1 + k0, &b_lds[p ^ 1][(w + 4) * 16][0]);
      asm volatile("s_waitcnt vmcnt(4)" ::: "memory");
    } else {
      asm volatile("s_waitcnt vmcnt(0)" ::: "memory");
    }
    __builtin_amdgcn_s_barrier();
    __builtin_amdgcn_sched_barrier(0);
    bf16x8 af[4], bfv[4];
#pragma unroll
    for (int mt = 0; mt < 4; ++mt)
      af[mt] = __builtin_bit_cast(bf16x8, *(const u32x4*)&a_lds[p][wr + mt * 16 + lr][lg * 8]);
#pragma unroll
    for (int nt = 0; nt < 4; ++nt)
      bfv[nt] = __builtin_bit_cast(bf16x8, *(const u32x4*)&b_lds[p][wc + nt * 16 + lr][lg * 8]);
    __builtin_amdgcn_s_setprio(1);
#pragma unroll
    for (int mt = 0; mt < 4; ++mt)
#pragma unroll
      for (int nt = 0; nt < 4; ++nt)
        acc[mt][nt] = __builtin_amdgcn_mfma_f32_16x16x32_bf16(af[mt], bfv[nt], acc[mt][nt], 0, 0, 0);
    __builtin_amdgcn_s_setprio(0);
    __builtin_amdgcn_sched_barrier(0);
    __builtin_amdgcn_s_barrier();
  }

  // ---- fused epilogue: RoPE + head-split ----
  int sec = n0 >> 10;                         // 0=Q 1=K 2=V
  int hcol = ((n0 + wc) & 1023) >> 6;         // head index
  u16* outp = (sec == 0) ? Qh : (sec == 1) ? Kh : Vh;
  float qscale = (sec == 0) ? 0.125f : 1.0f;
#pragma unroll
  for (int mt = 0; mt < 4; ++mt)
#pragma unroll
    for (int r = 0; r < 4; ++r) {
      int row = m0 + wr + mt * 16 + lg * 4 + r;
      int b = row >> 11, tt = row & 2047;
      size_t obase = ((size_t)((b * 16 + hcol) * 2048 + tt)) * 64;
      if (sec == 2) {
#pragma unroll
        for (int nt = 0; nt < 4; ++nt)
          outp[obase + nt * 16 + lr] = f2bf(acc[mt][nt][r]);
      } else {
        float c0 = cosT[tt * 32 + lr],      s0 = sinT[tt * 32 + lr];
        float c1 = cosT[tt * 32 + 16 + lr], s1 = sinT[tt * 32 + 16 + lr];
        float v0 = acc[mt][0][r], v1 = acc[mt][1][r];
        float v2 = acc[mt][2][r], v3 = acc[mt][3][r];
        outp[obase + lr]      = f2bf((v0 * c0 - v2 * s0) * qscale);
        outp[obase + 16 + lr] = f2bf((v1 * c1 - v3 * s1) * qscale);
        outp[obase + 32 + lr] = f2bf((v2 * c0 + v0 * s0) * qscale);
        outp[obase + 48 + lr] = f2bf((v3 * c1 + v1 * s1) * qscale);
      }
    }
}

// ---------------- GEMM out: aout[4096][1024] @ woutT -> fp32, 128x64 tiles ----------------
__global__ __launch_bounds__(256) void k_gemm_out(const u16* __restrict__ A,
                                                  const u16* __restrict__ Bt,
                                                  float* __restrict__ C) {
  const int N = 1024, K = 1024;
  __shared__ __align__(16) u16 a_lds[2][128][32];
  __shared__ __align__(16) u16 b_lds[2][64][32];
  int m0 = blockIdx.y * 128, n0 = blockIdx.x * 64;
  int tid = threadIdx.x;
  int w = tid >> 6, l = tid & 63, lr = l & 15, lg = l >> 4;
  int wr = (w >> 1) * 64, wc = (w & 1) * 32;
  int grow = l >> 2;
  int gcol = (l & 3) * 8;
  f32x4 acc[4][2] = {};

  const u16* a0 = A + (size_t)(m0 + w * 16 + grow) * K + gcol;
  const u16* a1 = A + (size_t)(m0 + (w + 4) * 16 + grow) * K + gcol;
  const u16* b0 = Bt + (size_t)(n0 + w * 16 + grow) * K + gcol;

  int NT = K >> 5;
  GLDS(a0, &a_lds[0][w * 16][0]);
  GLDS(a1, &a_lds[0][(w + 4) * 16][0]);
  GLDS(b0, &b_lds[0][w * 16][0]);

  for (int t = 0; t < NT; ++t) {
    int p = t & 1;
    if (t + 1 < NT) {
      int k0 = (t + 1) << 5;
      GLDS(a0 + k0, &a_lds[p ^ 1][w * 16][0]);
      GLDS(a1 + k0, &a_lds[p ^ 1][(w + 4) * 16][0]);
      GLDS(b0 + k0, &b_lds[p ^ 1][w * 16][0]);
      asm volatile("s_waitcnt vmcnt(3)" ::: "memory");
    } else {
      asm volatile("s_waitcnt vmcnt(0)" ::: "memory");
    }
    __builtin_amdgcn_s_barrier();
    __builtin_amdgcn_sched_barrier(0);
    bf16x8 af[4], bfv[2];
#pragma unroll
    for (int mt = 0; mt < 4; ++mt)
      af[mt] = __builtin_bit_cast(bf16x8, *(const u32x4*)&a_lds[p][wr + mt * 16 + lr][lg * 8]);
#pragma unroll
    for (int nt = 0; nt < 2; ++nt)
      bfv[nt] = __builtin_bit_cast(bf16x8, *(const u32x4*)&b_lds[p][wc + nt * 16 + lr][lg * 8]);
    __builtin_amdgcn_s_setprio(1);
#pragma unroll
    for (int mt = 0; mt < 4; ++mt)
#pragma unroll
      for (int nt = 0; nt < 2; ++nt)
        acc[mt][nt] = __builtin_amdgcn_mfma_f32_16x16x32_bf16(af[mt], bfv[nt], acc[mt][nt], 0, 0, 0);
    __builtin_amdgcn_s_setprio(0);
    __builtin_amdgcn_sched_barrier(0);
    __builtin_amdgcn_s_barrier();
  }

#pragma unroll
  for (int mt = 0; mt < 4; ++mt)
#pragma unroll
    for (int nt = 0; nt < 2; ++nt)
#pragma unroll
      for (int r = 0; r < 4; ++r) {
        int row = m0 + wr + mt * 16 + lg * 4 + r;
        int col = n0 + wc + nt * 16 + lr;
        C[(size_t)row * N + col] = acc[mt][nt][r];
      }
}

// ---------------- flash attention: merged-pair KV loop ----------------
// Block p owns q-tiles qb1=31-p (heavy) and qb2=p (light). qb2 < qb1 always, so
// tile2's KV range is a prefix: ONE kv loop of qb1+1 iters, tile2 computed while
// kv <= qb2. Fixed overhead iters: 33 -> 32-p (avg 24.5).
__global__ __launch_bounds__(256) void k_flash(const u16* __restrict__ Qg, const u16* __restrict__ Kg,
                                               const u16* __restrict__ Vg, u16* __restrict__ O) {
  __shared__ __align__(16) u16 k_lds[2][64][72];
  __shared__ __align__(16) u16 vsub[2][4096];
  __shared__ __align__(16) u16 p_lds[4][16][68];
  int pp = blockIdx.x;                  // 0..15
  int qb1 = 31 - pp, qb2 = pp;
  int bh = blockIdx.y;
  int b = bh >> 4, h = bh & 15;
  size_t hoff = (size_t)bh * TSEQ * DHEAD;
  int tid = threadIdx.x, w = tid >> 6, l = tid & 63, lr = l & 15, lg = l >> 4;

  int srow = tid >> 3;
  int g8 = tid & 7;
  int sc8 = g8 * 8;
  u32 vtr0 = (u32)(uintptr_t)vsub + (u32)(lg * 1024 + lr * 8);

  const u16* kbase = Kg + hoff;
  const u16* vbase = Vg + hoff;

  // Q fragments for both tiles
  const u16* qp1 = Qg + hoff + (size_t)(qb1 * 64 + w * 16 + lr) * 64 + lg * 8;
  const u16* qp2 = Qg + hoff + (size_t)(qb2 * 64 + w * 16 + lr) * 64 + lg * 8;
  bf16x8 qf0 = __builtin_bit_cast(bf16x8, *(const u32x4*)qp1);
  bf16x8 qf1 = __builtin_bit_cast(bf16x8, *(const u32x4*)(qp1 + 32));
  bf16x8 qg0 = __builtin_bit_cast(bf16x8, *(const u32x4*)qp2);
  bf16x8 qg1 = __builtin_bit_cast(bf16x8, *(const u32x4*)(qp2 + 32));

  f32x4 acc1[4] = {}, acc2[4] = {};
  float m1[4] = {-1e30f, -1e30f, -1e30f, -1e30f}, m2[4] = {-1e30f, -1e30f, -1e30f, -1e30f};
  float l1[4] = {0.f, 0.f, 0.f, 0.f}, l2[4] = {0.f, 0.f, 0.f, 0.f};  // lane-partial

  u32x4 kreg[2], vreg[2];
#pragma unroll
  for (int p = 0; p < 2; ++p) {
    int r = srow + p * 32;
    kreg[p] = *(const u32x4*)(kbase + (size_t)r * 64 + sc8);
    vreg[p] = *(const u32x4*)(vbase + (size_t)r * 64 + sc8);
  }

  for (int kv = 0; kv <= qb1; ++kv) {
    int cur = kv & 1;
#pragma unroll
    for (int p = 0; p < 2; ++p) {
      int r = srow + p * 32;
      *(u32x4*)&k_lds[cur][r][sc8] = kreg[p];
      int vo = ((r >> 2) * 4 + (g8 >> 1)) * 64 + (r & 3) * 16 + (g8 & 1) * 8;
      *(u32x4*)&vsub[cur][vo] = vreg[p];
    }
    __syncthreads();
    if (kv < qb1) {
#pragma unroll
      for (int p = 0; p < 2; ++p) {
        int r = (kv + 1) * 64 + srow + p * 32;
        kreg[p] = *(const u32x4*)(kbase + (size_t)r * 64 + sc8);
        vreg[p] = *(const u32x4*)(vbase + (size_t)r * 64 + sc8);
      }
    }
    u32 vtr = vtr0 + (u32)(cur * 8192);

    // K fragments once, shared by both tiles
    bf16x8 kf0[4], kf1[4];
#pragma unroll
    for (int c = 0; c < 4; ++c) {
      const u16* kp2 = &k_lds[cur][c * 16 + lr][lg * 8];
      kf0[c] = __builtin_bit_cast(bf16x8, *(const u32x4*)kp2);
      kf1[c] = __builtin_bit_cast(bf16x8, *(const u32x4*)(kp2 + 32));
    }

    // ---- tile 1 (heavy) ----
    {
      f32x4 s[4];
      __builtin_amdgcn_s_setprio(1);
#pragma unroll
      for (int c = 0; c < 4; ++c) {
        f32x4 z = {};
        z = __builtin_amdgcn_mfma_f32_16x16x32_bf16(qf0, kf0[c], z, 0, 0, 0);
        s[c] = __builtin_amdgcn_mfma_f32_16x16x32_bf16(qf1, kf1[c], z, 0, 0, 0);
      }
      __builtin_amdgcn_s_setprio(0);
      if (kv == qb1) {
#pragma unroll
        for (int c = 0; c < 4; ++c)
#pragma unroll
          for (int r = 0; r < 4; ++r)
            if (c * 16 + lr > w * 16 + lg * 4 + r) s[c][r] = -1e30f;
      }
      float rmax[4];
#pragma unroll
      for (int r = 0; r < 4; ++r)
        rmax[r] = fmaxf(fmaxf(s[0][r], s[1][r]), fmaxf(s[2][r], s[3][r]));
#pragma unroll
      for (int mset = 1; mset <= 8; mset <<= 1)
#pragma unroll
        for (int r = 0; r < 4; ++r)
          rmax[r] = fmaxf(rmax[r], __shfl_xor(rmax[r], mset, 64));
      bool need = (rmax[0] > m1[0] + 8.0f) | (rmax[1] > m1[1] + 8.0f) |
                  (rmax[2] > m1[2] + 8.0f) | (rmax[3] > m1[3] + 8.0f);
      if (__any(need)) {
        float alpha[4];
#pragma unroll
        for (int r = 0; r < 4; ++r) {
          float mn = fmaxf(m1[r], rmax[r]);
          alpha[r] = __expf(m1[r] - mn);
          m1[r] = mn;
          l1[r] *= alpha[r];
        }
#pragma unroll
        for (int n = 0; n < 4; ++n)
#pragma unroll
          for (int r = 0; r < 4; ++r)
            acc1[n][r] *= alpha[r];
      }
#pragma unroll
      for (int c = 0; c < 4; ++c)
#pragma unroll
        for (int r = 0; r < 4; ++r) {
          float pe = __expf(s[c][r] - m1[r]);
          s[c][r] = pe;
          l1[r] += pe;
        }
#pragma unroll
      for (int c = 0; c < 4; ++c)
#pragma unroll
        for (int r = 0; r < 4; ++r)
          p_lds[w][lg * 4 + r][c * 16 + lr] = f2bf(s[c][r]);
      bf16x8 pa0 = __builtin_bit_cast(bf16x8, *(const u32x4*)&p_lds[w][lr][lg * 8]);
      bf16x8 pa1 = __builtin_bit_cast(bf16x8, *(const u32x4*)&p_lds[w][lr][lg * 8 + 32]);
      {
        u32x2 t[8];
        TRR(t[0], vtr, "0");    TRR(t[1], vtr, "512");
        TRR(t[2], vtr, "4096"); TRR(t[3], vtr, "4608");
        TRR(t[4], vtr, "128");  TRR(t[5], vtr, "640");
        TRR(t[6], vtr, "4224"); TRR(t[7], vtr, "4736");
        asm volatile("s_waitcnt lgkmcnt(0)" ::: "memory");
        __builtin_amdgcn_sched_barrier(0);
        __builtin_amdgcn_s_setprio(1);
#pragma unroll
        for (int n2 = 0; n2 < 2; ++n2) {
          u32x4 vlo, vhi;
          vlo[0] = t[n2 * 4 + 0][0]; vlo[1] = t[n2 * 4 + 0][1];
          vlo[2] = t[n2 * 4 + 1][0]; vlo[3] = t[n2 * 4 + 1][1];
          vhi[0] = t[n2 * 4 + 2][0]; vhi[1] = t[n2 * 4 + 2][1];
          vhi[2] = t[n2 * 4 + 3][0]; vhi[3] = t[n2 * 4 + 3][1];
          acc1[n2] = __builtin_amdgcn_mfma_f32_16x16x32_bf16(pa0, __builtin_bit_cast(bf16x8, vlo), acc1[n2], 0, 0, 0);
          acc1[n2] = __builtin_amdgcn_mfma_f32_16x16x32_bf16(pa1, __builtin_bit_cast(bf16x8, vhi), acc1[n2], 0, 0, 0);
        }
        __builtin_amdgcn_s_setprio(0);
      }
      {
        u32x2 t[8];
        TRR(t[0], vtr, "256");  TRR(t[1], vtr, "768");
        TRR(t[2], vtr, "4352"); TRR(t[3], vtr, "4864");
        TRR(t[4], vtr, "384");  TRR(t[5], vtr, "896");
        TRR(t[6], vtr, "4480"); TRR(t[7], vtr, "4992");
        asm volatile("s_waitcnt lgkmcnt(0)" ::: "memory");
        __builtin_amdgcn_sched_barrier(0);
        __builtin_amdgcn_s_setprio(1);
#pragma unroll
        for (int n2 = 0; n2 < 2; ++n2) {
          int n = 2 + n2;
          u32x4 vlo, vhi;
          vlo[0] = t[n2 * 4 + 0][0]; vlo[1] = t[n2 * 4 + 0][1];
          vlo[2] = t[n2 * 4 + 1][0]; vlo[3] = t[n2 * 4 + 1][1];
          vhi[0] = t[n2 * 4 + 2][0]; vhi[1] = t[n2 * 4 + 2][1];
          vhi[2] = t[n2 * 4 + 3][0]; vhi[3] = t[n2 * 4 + 3][1];
          acc1[n] = __builtin_amdgcn_mfma_f32_16x16x32_bf16(pa0, __builtin_bit_cast(bf16x8, vlo), acc1[n], 0, 0, 0);
          acc1[n] = __builtin_amdgcn_mfma_f32_16x16x32_bf16(pa1, __builtin_bit_cast(bf16x8, vhi), acc1[n], 0, 0, 0);
        }
        __builtin_amdgcn_s_setprio(0);
      }
    }

    // ---- tile 2 (light), only while kv <= qb2 ----
    if (kv <= qb2) {
      f32x4 s[4];
      __builtin_amdgcn_s_setprio(1);
#pragma unroll
      for (int c = 0; c < 4; ++c) {
        f32x4 z = {};
        z = __builtin_amdgcn_mfma_f32_16x16x32_bf16(qg0, kf0[c], z, 0, 0, 0);
        s[c] = __builtin_amdgcn_mfma_f32_16x16x32_bf16(qg1, kf1[c], z, 0, 0, 0);
      }
      __builtin_amdgcn_s_setprio(0);
      if (kv == qb2) {
#pragma unroll
        for (int c = 0; c < 4; ++c)
#pragma unroll
          for (int r = 0; r < 4; ++r)
            if (c * 16 + lr > w * 16 + lg * 4 + r) s[c][r] = -1e30f;
      }
      float rmax[4];
#pragma unroll
      for (int r = 0; r < 4; ++r)
        rmax[r] = fmaxf(fmaxf(s[0][r], s[1][r]), fmaxf(s[2][r], s[3][r]));
#pragma unroll
      for (int mset = 1; mset <= 8; mset <<= 1)
#pragma unroll
        for (int r = 0; r < 4; ++r)
          rmax[r] = fmaxf(rmax[r], __shfl_xor(rmax[r], mset, 64));
      bool need = (rmax[0] > m2[0] + 8.0f) | (rmax[1] > m2[1] + 8.0f) |
                  (rmax[2] > m2[2] + 8.0f) | (rmax[3] > m2[3] + 8.0f);
      if (__any(need)) {
        float alpha[4];
#pragma unroll
        for (int r = 0; r < 4; ++r) {
          float mn = fmaxf(m2[r], rmax[r]);
          alpha[r] = __expf(m2[r] - mn);
          m2[r] = mn;
          l2[r] *= alpha[r];
        }
#pragma unroll
        for (int n = 0; n < 4; ++n)
#pragma unroll
          for (int r = 0; r < 4; ++r)
            acc2[n][r] *= alpha[r];
      }
#pragma unroll
      for (int c = 0; c < 4; ++c)
#pragma unroll
        for (int r = 0; r < 4; ++r) {
          float pe = __expf(s[c][r] - m2[r]);
          s[c][r] = pe;
          l2[r] += pe;
        }
#pragma unroll
      for (int c = 0; c < 4; ++c)
#pragma unroll
        for (int r = 0; r < 4; ++r)
          p_lds[w][lg * 4 + r][c * 16 + lr] = f2bf(s[c][r]);
      bf16x8 pa0 = __builtin_bit_cast(bf16x8, *(const u32x4*)&p_lds[w][lr][lg * 8]);
      bf16x8 pa1 = __builtin_bit_cast(bf16x8, *(const u32x4*)&p_lds[w][lr][lg * 8 + 32]);
      {
        u32x2 t[8];
        TRR(t[0], vtr, "0");    TRR(t[1], vtr, "512");
        TRR(t[2], vtr, "4096"); TRR(t[3], vtr, "4608");
        TRR(t[4], vtr, "128");  TRR(t[5], vtr, "640");
        TRR(t[6], vtr, "4224"); TRR(t[7], vtr, "4736");
        asm volatile("s_waitcnt lgkmcnt(0)" ::: "memory");
        __builtin_amdgcn_sched_barrier(0);
        __builtin_amdgcn_s_setprio(1);
#pragma unroll
        for (int n2 = 0; n2 < 2; ++n2) {
          u32x4 vlo, vhi;
          vlo[0] = t[n2 * 4 + 0][0]; vlo[1] = t[n2 * 4 + 0][1];
          vlo[2] = t[n2 * 4 + 1][0]; vlo[3] = t[n2 * 4 + 1][1];
          vhi[0] = t[n2 * 4 + 2][0]; vhi[1] = t[n2 * 4 + 2][1];
          vhi[2] = t[n2 * 4 + 3][0]; vhi[3] = t[n2 * 4 + 3][1];
          acc2[n2] = __builtin_amdgcn_mfma_f32_16x16x32_bf16(pa0, __builtin_bit_cast(bf16x8, vlo), acc2[n2], 0, 0, 0);
          acc2[n2] = __builtin_amdgcn_mfma_f32_16x16x32_bf16(pa1, __builtin_bit_cast(bf16x8, vhi), acc2[n2], 0, 0, 0);
        }
        __builtin_amdgcn_s_setprio(0);
      }
      {
        u32x2 t[8];
        TRR(t[0], vtr, "256");  TRR(t[1], vtr, "768");
        TRR(t[2], vtr, "4352"); TRR(t[3], vtr, "4864");
        TRR(t[4], vtr, "384");  TRR(t[5], vtr, "896");
        TRR(t[6], vtr, "4480"); TRR(t[7], vtr, "4992");
        asm volatile("s_waitcnt lgkmcnt(0)" ::: "memory");
        __builtin_amdgcn_sched_barrier(0);
        __builtin_amdgcn_s_setprio(1);
#pragma unroll
        for (int n2 = 0; n2 < 2; ++n2) {
          int n = 2 + n2;
          u32x4 vlo, vhi;
          vlo[0] = t[n2 * 4 + 0][0]; vlo[1] = t[n2 * 4 + 0][1];
          vlo[2] = t[n2 * 4 + 1][0]; vlo[3] = t[n2 * 4 + 1][1];
          vhi[0] = t[n2 * 4 + 2][0]; vhi[1] = t[n2 * 4 + 2][1];
          vhi[2] = t[n2 * 4 + 3][0]; vhi[3] = t[n2 * 4 + 3][1];
          acc2[n] = __builtin_amdgcn_mfma_f32_16x16x32_bf16(pa0, __builtin_bit_cast(bf16x8, vlo), acc2[n], 0, 0, 0);
          acc2[n] = __builtin_amdgcn_mfma_f32_16x16x32_bf16(pa1, __builtin_bit_cast(bf16x8, vhi), acc2[n], 0, 0, 0);
        }
        __builtin_amdgcn_s_setprio(0);
      }
    }
  }

  // epilogue: reduce lane-partial sums, normalize, write both tiles
#pragma unroll
  for (int mset = 1; mset <= 8; mset <<= 1)
#pragma unroll
    for (int r = 0; r < 4; ++r) {
      l1[r] += __shfl_xor(l1[r], mset, 64);
      l2[r] += __shfl_xor(l2[r], mset, 64);
    }
#pragma unroll
  for (int n = 0; n < 4; ++n)
#pragma unroll
    for (int r = 0; r < 4; ++r) {
      int t1 = qb1 * 64 + w * 16 + lg * 4 + r;
      int t2 = qb2 * 64 + w * 16 + lg * 4 + r;
      int dd = n * 16 + lr;
      O[(size_t)(b * TSEQ + t1) * DMODEL + h * 64 + dd] = f2bf(acc1[n][r] / l1[r]);
      O[(size_t)(b * TSEQ + t2) * DMODEL + h * 64 + dd] = f2bf(acc2[n][r] / l2[r]);
    }
}

extern "C" void kernel_launch(void* const* d_in, const int* in_sizes, int n_in,
                              void* d_out, int out_size, void* d_ws, size_t ws_size,
                              hipStream_t stream) {
  const float* x     = (const float*)d_in[0];
  const float* w_qkv = (const float*)d_in[1];
  const float* w_out = (const float*)d_in[2];
  float* out = (float*)d_out;

  char* ws = (char*)d_ws;
  size_t off = 0;
  auto alloc = [&](size_t bytes) {
    char* p = ws + off;
    off += (bytes + 255) & ~(size_t)255;
    return p;
  };
  const size_t MT = (size_t)BSZ * TSEQ;  // 4096
  u16* xb    = (u16*)alloc(MT * DMODEL * 2);
  u16* wqkvT = (u16*)alloc((size_t)3 * DMODEL * DMODEL * 2);
  u16* woutT = (u16*)alloc((size_t)DMODEL * DMODEL * 2);
  u16* Qh    = (u16*)alloc(MT * DMODEL * 2);
  u16* Kh    = (u16*)alloc(MT * DMODEL * 2);
  u16* Vh    = (u16*)alloc(MT * DMODEL * 2);
  u16* aout  = (u16*)alloc(MT * DMODEL * 2);
  float* cosT = (float*)alloc((size_t)TSEQ * 32 * 4);
  float* sinT = (float*)alloc((size_t)TSEQ * 32 * 4);
  if (ws_size < off) return;

  k_prep<<<3328, 256, 0, stream>>>(x, xb, w_qkv, wqkvT, w_out, woutT, cosT, sinT);
  k_gemm_qkv<<<dim3(24, 32), 256, 0, stream>>>(xb, wqkvT, Qh, Kh, Vh, cosT, sinT);
  k_flash<<<dim3(16, BSZ * NHEAD), 256, 0, stream>>>(Qh, Kh, Vh, aout);
  k_gemm_out<<<dim3(16, 32), 256, 0, stream>>>(aout, woutT, out);
}

// Round 10
// 199.339 us; speedup vs baseline: 1.5600x; 1.0152x over previous
//
#include <hip/hip_runtime.h>

typedef __bf16 bf16x8 __attribute__((ext_vector_type(8)));
typedef float f32x4 __attribute__((ext_vector_type(4)));
typedef unsigned int u32x4 __attribute__((ext_vector_type(4)));
typedef unsigned int u32x2 __attribute__((ext_vector_type(2)));
typedef unsigned short u16;
typedef unsigned int u32;

#define BSZ 2
#define TSEQ 2048
#define DMODEL 1024
#define NHEAD 16
#define DHEAD 64

#define GLDS(gp, lp)                                                        \
  __builtin_amdgcn_global_load_lds(                                         \
      (const __attribute__((address_space(1))) void*)(gp),                  \
      (__attribute__((address_space(3))) void*)(lp), 16, 0, 0)

#define TRR(dst, base, OFF)                                                 \
  asm volatile("ds_read_b64_tr_b16 %0, %1 offset:" OFF                     \
               : "=v"(dst) : "v"(base) : "memory")

__device__ __forceinline__ u16 f2bf(float f) {
  return __builtin_bit_cast(u16, (__bf16)f);
}
__device__ __forceinline__ u32 pack2bf(float lo, float hi) {
  return (u32)f2bf(lo) | ((u32)f2bf(hi) << 16);
}
__device__ __forceinline__ float bf2f(u16 h) {
  return __builtin_bit_cast(float, (u32)h << 16);
}

// ---------- fused pre-pass: cvt x | transpose wqkv | transpose wout | rope table ----------
__global__ void k_prep(const float* __restrict__ x, u16* __restrict__ xb,
                       const float* __restrict__ wqkv, u16* __restrict__ wqkvT,
                       const float* __restrict__ wout, u16* __restrict__ woutT,
                       float* __restrict__ cosT, float* __restrict__ sinT) {
  __shared__ float tile[64][65];
  int blk = blockIdx.x, tid = threadIdx.x;
  if (blk < 2048) {                       // cvt x -> bf16, 8 elems/thread
    int i = blk * 256 + tid;
    const float4* f4 = (const float4*)x;
    float4 v0 = f4[i * 2], v1 = f4[i * 2 + 1];
    u32x4 o;
    o[0] = pack2bf(v0.x, v0.y); o[1] = pack2bf(v0.z, v0.w);
    o[2] = pack2bf(v1.x, v1.y); o[3] = pack2bf(v1.z, v1.w);
    ((u32x4*)xb)[i] = o;
  } else if (blk < 2816) {                // transpose wqkv [1024][3072] -> [3072][1024]
    int idx = blk - 2048;
    int n0 = (idx % 48) * 64, k0 = (idx / 48) * 64;
    int tx = tid & 63, ty = tid >> 6;
#pragma unroll
    for (int i = ty; i < 64; i += 4)
      tile[i][tx] = wqkv[(size_t)(k0 + i) * 3072 + n0 + tx];
    __syncthreads();
#pragma unroll
    for (int i = ty; i < 64; i += 4)
      wqkvT[(size_t)(n0 + i) * 1024 + k0 + tx] = f2bf(tile[tx][i]);
  } else if (blk < 3072) {                // transpose wout [1024][1024]
    int idx = blk - 2816;
    int n0 = (idx % 16) * 64, k0 = (idx / 16) * 64;
    int tx = tid & 63, ty = tid >> 6;
#pragma unroll
    for (int i = ty; i < 64; i += 4)
      tile[i][tx] = wout[(size_t)(k0 + i) * 1024 + n0 + tx];
    __syncthreads();
#pragma unroll
    for (int i = ty; i < 64; i += 4)
      woutT[(size_t)(n0 + i) * 1024 + k0 + tx] = f2bf(tile[tx][i]);
  } else {                                // rope table [2048][32]
    int idx = (blk - 3072) * 256 + tid;
    int t = idx >> 5, f = idx & 31;
    float inv_freq = powf(10000.0f, -(float)(2 * f) / 64.0f);
    float ang = (float)t * inv_freq;
    float s, c;
    sincosf(ang, &s, &c);
    cosT[idx] = c;
    sinT[idx] = s;
  }
}

// ---------------- GEMM1 fused: x @ w_qkv with RoPE+split epilogue ----------------
__global__ __launch_bounds__(256) void k_gemm_qkv(const u16* __restrict__ A,
                                                  const u16* __restrict__ Bt,
                                                  u16* __restrict__ Qh, u16* __restrict__ Kh,
                                                  u16* __restrict__ Vh,
                                                  const float* __restrict__ cosT,
                                                  const float* __restrict__ sinT) {
  const int K = DMODEL;
  __shared__ __align__(16) u16 a_lds[2][128][32];
  __shared__ __align__(16) u16 b_lds[2][128][32];
  int m0 = blockIdx.y * 128, n0 = blockIdx.x * 128;
  int tid = threadIdx.x;
  int w = tid >> 6, l = tid & 63, lr = l & 15, lg = l >> 4;
  int wr = (w >> 1) * 64, wc = (w & 1) * 64;
  int grow = l >> 2;
  int gcol = (l & 3) * 8;
  f32x4 acc[4][4] = {};

  const u16* a0 = A + (size_t)(m0 + w * 16 + grow) * K + gcol;
  const u16* a1 = A + (size_t)(m0 + (w + 4) * 16 + grow) * K + gcol;
  const u16* b0 = Bt + (size_t)(n0 + w * 16 + grow) * K + gcol;
  const u16* b1 = Bt + (size_t)(n0 + (w + 4) * 16 + grow) * K + gcol;

  int NT = K >> 5;
  GLDS(a0, &a_lds[0][w * 16][0]);
  GLDS(a1, &a_lds[0][(w + 4) * 16][0]);
  GLDS(b0, &b_lds[0][w * 16][0]);
  GLDS(b1, &b_lds[0][(w + 4) * 16][0]);

  for (int t = 0; t < NT; ++t) {
    int p = t & 1;
    if (t + 1 < NT) {
      int k0 = (t + 1) << 5;
      GLDS(a0 + k0, &a_lds[p ^ 1][w * 16][0]);
      GLDS(a1 + k0, &a_lds[p ^ 1][(w + 4) * 16][0]);
      GLDS(b0 + k0, &b_lds[p ^ 1][w * 16][0]);
      GLDS(b1 + k0, &b_lds[p ^ 1][(w + 4) * 16][0]);
      asm volatile("s_waitcnt vmcnt(4)" ::: "memory");
    } else {
      asm volatile("s_waitcnt vmcnt(0)" ::: "memory");
    }
    __builtin_amdgcn_s_barrier();
    __builtin_amdgcn_sched_barrier(0);
    bf16x8 af[4], bfv[4];
#pragma unroll
    for (int mt = 0; mt < 4; ++mt)
      af[mt] = __builtin_bit_cast(bf16x8, *(const u32x4*)&a_lds[p][wr + mt * 16 + lr][lg * 8]);
#pragma unroll
    for (int nt = 0; nt < 4; ++nt)
      bfv[nt] = __builtin_bit_cast(bf16x8, *(const u32x4*)&b_lds[p][wc + nt * 16 + lr][lg * 8]);
    __builtin_amdgcn_s_setprio(1);
#pragma unroll
    for (int mt = 0; mt < 4; ++mt)
#pragma unroll
      for (int nt = 0; nt < 4; ++nt)
        acc[mt][nt] = __builtin_amdgcn_mfma_f32_16x16x32_bf16(af[mt], bfv[nt], acc[mt][nt], 0, 0, 0);
    __builtin_amdgcn_s_setprio(0);
    __builtin_amdgcn_sched_barrier(0);
    __builtin_amdgcn_s_barrier();
  }

  // ---- fused epilogue: RoPE + head-split ----
  int sec = n0 >> 10;                         // 0=Q 1=K 2=V
  int hcol = ((n0 + wc) & 1023) >> 6;         // head index
  u16* outp = (sec == 0) ? Qh : (sec == 1) ? Kh : Vh;
  float qscale = (sec == 0) ? 0.125f : 1.0f;
#pragma unroll
  for (int mt = 0; mt < 4; ++mt)
#pragma unroll
    for (int r = 0; r < 4; ++r) {
      int row = m0 + wr + mt * 16 + lg * 4 + r;
      int b = row >> 11, tt = row & 2047;
      size_t obase = ((size_t)((b * 16 + hcol) * 2048 + tt)) * 64;
      if (sec == 2) {
#pragma unroll
        for (int nt = 0; nt < 4; ++nt)
          outp[obase + nt * 16 + lr] = f2bf(acc[mt][nt][r]);
      } else {
        float c0 = cosT[tt * 32 + lr],      s0 = sinT[tt * 32 + lr];
        float c1 = cosT[tt * 32 + 16 + lr], s1 = sinT[tt * 32 + 16 + lr];
        float v0 = acc[mt][0][r], v1 = acc[mt][1][r];
        float v2 = acc[mt][2][r], v3 = acc[mt][3][r];
        outp[obase + lr]      = f2bf((v0 * c0 - v2 * s0) * qscale);
        outp[obase + 16 + lr] = f2bf((v1 * c1 - v3 * s1) * qscale);
        outp[obase + 32 + lr] = f2bf((v2 * c0 + v0 * s0) * qscale);
        outp[obase + 48 + lr] = f2bf((v3 * c1 + v1 * s1) * qscale);
      }
    }
}

// ---------------- GEMM out: aout[4096][1024] @ woutT -> fp32, 128x64 tiles ----------------
__global__ __launch_bounds__(256) void k_gemm_out(const u16* __restrict__ A,
                                                  const u16* __restrict__ Bt,
                                                  float* __restrict__ C) {
  const int N = 1024, K = 1024;
  __shared__ __align__(16) u16 a_lds[2][128][32];
  __shared__ __align__(16) u16 b_lds[2][64][32];
  int m0 = blockIdx.y * 128, n0 = blockIdx.x * 64;
  int tid = threadIdx.x;
  int w = tid >> 6, l = tid & 63, lr = l & 15, lg = l >> 4;
  int wr = (w >> 1) * 64, wc = (w & 1) * 32;
  int grow = l >> 2;
  int gcol = (l & 3) * 8;
  f32x4 acc[4][2] = {};

  const u16* a0 = A + (size_t)(m0 + w * 16 + grow) * K + gcol;
  const u16* a1 = A + (size_t)(m0 + (w + 4) * 16 + grow) * K + gcol;
  const u16* b0 = Bt + (size_t)(n0 + w * 16 + grow) * K + gcol;

  int NT = K >> 5;
  GLDS(a0, &a_lds[0][w * 16][0]);
  GLDS(a1, &a_lds[0][(w + 4) * 16][0]);
  GLDS(b0, &b_lds[0][w * 16][0]);

  for (int t = 0; t < NT; ++t) {
    int p = t & 1;
    if (t + 1 < NT) {
      int k0 = (t + 1) << 5;
      GLDS(a0 + k0, &a_lds[p ^ 1][w * 16][0]);
      GLDS(a1 + k0, &a_lds[p ^ 1][(w + 4) * 16][0]);
      GLDS(b0 + k0, &b_lds[p ^ 1][w * 16][0]);
      asm volatile("s_waitcnt vmcnt(3)" ::: "memory");
    } else {
      asm volatile("s_waitcnt vmcnt(0)" ::: "memory");
    }
    __builtin_amdgcn_s_barrier();
    __builtin_amdgcn_sched_barrier(0);
    bf16x8 af[4], bfv[2];
#pragma unroll
    for (int mt = 0; mt < 4; ++mt)
      af[mt] = __builtin_bit_cast(bf16x8, *(const u32x4*)&a_lds[p][wr + mt * 16 + lr][lg * 8]);
#pragma unroll
    for (int nt = 0; nt < 2; ++nt)
      bfv[nt] = __builtin_bit_cast(bf16x8, *(const u32x4*)&b_lds[p][wc + nt * 16 + lr][lg * 8]);
    __builtin_amdgcn_s_setprio(1);
#pragma unroll
    for (int mt = 0; mt < 4; ++mt)
#pragma unroll
      for (int nt = 0; nt < 2; ++nt)
        acc[mt][nt] = __builtin_amdgcn_mfma_f32_16x16x32_bf16(af[mt], bfv[nt], acc[mt][nt], 0, 0, 0);
    __builtin_amdgcn_s_setprio(0);
    __builtin_amdgcn_sched_barrier(0);
    __builtin_amdgcn_s_barrier();
  }

#pragma unroll
  for (int mt = 0; mt < 4; ++mt)
#pragma unroll
    for (int nt = 0; nt < 2; ++nt)
#pragma unroll
      for (int r = 0; r < 4; ++r) {
        int row = m0 + wr + mt * 16 + lg * 4 + r;
        int col = n0 + wc + nt * 16 + lr;
        C[(size_t)row * N + col] = acc[mt][nt][r];
      }
}

// ---------------- flash attention: 8-wave blocks, shared K/V staging ----------------
// Block p: waves 0-3 compute tile qb1=31-p, waves 4-7 compute tile qb2=p. One
// K/V stage + barrier per kv serves both. Light team idles past qb2, freeing
// its SIMD issue slots to the heavy team. 512 blocks x 8 waves = 16 waves/CU.
__global__ __launch_bounds__(512) void k_flash(const u16* __restrict__ Qg, const u16* __restrict__ Kg,
                                               const u16* __restrict__ Vg, u16* __restrict__ O) {
  __shared__ __align__(16) u16 k_lds[2][64][72];
  __shared__ __align__(16) u16 vsub[2][4096];
  __shared__ __align__(16) u16 p_lds[8][16][68];
  int pp = blockIdx.x;                  // 0..15
  int qb1 = 31 - pp, qb2 = pp;
  int bh = blockIdx.y;
  int b = bh >> 4, h = bh & 15;
  size_t hoff = (size_t)bh * TSEQ * DHEAD;
  int tid = threadIdx.x, w = tid >> 6, l = tid & 63, lr = l & 15, lg = l >> 4;
  int team = w >> 2, wt = w & 3;
  int qb_t = team ? qb2 : qb1;

  int srow = tid >> 3;        // 0..63: one staging row per thread
  int g8 = tid & 7;
  int sc8 = g8 * 8;
  u32 vtr0 = (u32)(uintptr_t)vsub + (u32)(lg * 1024 + lr * 8);

  const u16* kbase = Kg + hoff;
  const u16* vbase = Vg + hoff;

  // Q fragments for this wave's tile
  const u16* qp = Qg + hoff + (size_t)(qb_t * 64 + wt * 16 + lr) * 64 + lg * 8;
  bf16x8 qf0 = __builtin_bit_cast(bf16x8, *(const u32x4*)qp);
  bf16x8 qf1 = __builtin_bit_cast(bf16x8, *(const u32x4*)(qp + 32));

  f32x4 acc[4] = {};
  float mrow[4] = {-1e30f, -1e30f, -1e30f, -1e30f};
  float lsum[4] = {0.f, 0.f, 0.f, 0.f};   // lane-partial

  u32x4 kreg, vreg;
  kreg = *(const u32x4*)(kbase + (size_t)srow * 64 + sc8);
  vreg = *(const u32x4*)(vbase + (size_t)srow * 64 + sc8);

  for (int kv = 0; kv <= qb1; ++kv) {
    int cur = kv & 1;
    *(u32x4*)&k_lds[cur][srow][sc8] = kreg;
    int vo = ((srow >> 2) * 4 + (g8 >> 1)) * 64 + (srow & 3) * 16 + (g8 & 1) * 8;
    *(u32x4*)&vsub[cur][vo] = vreg;
    __syncthreads();   // buf[cur] ready; buf[cur^1] free
    if (kv < qb1) {
      int r = (kv + 1) * 64 + srow;
      kreg = *(const u32x4*)(kbase + (size_t)r * 64 + sc8);
      vreg = *(const u32x4*)(vbase + (size_t)r * 64 + sc8);
    }

    if (kv <= qb_t) {
      u32 vtr = vtr0 + (u32)(cur * 8192);
      // S = (Q*scale) K^T  -- 16x64 per wave
      f32x4 s[4];
      __builtin_amdgcn_s_setprio(1);
#pragma unroll
      for (int c = 0; c < 4; ++c) {
        const u16* kp2 = &k_lds[cur][c * 16 + lr][lg * 8];
        bf16x8 kf0 = __builtin_bit_cast(bf16x8, *(const u32x4*)kp2);
        bf16x8 kf1 = __builtin_bit_cast(bf16x8, *(const u32x4*)(kp2 + 32));
        f32x4 z = {};
        z = __builtin_amdgcn_mfma_f32_16x16x32_bf16(qf0, kf0, z, 0, 0, 0);
        s[c] = __builtin_amdgcn_mfma_f32_16x16x32_bf16(qf1, kf1, z, 0, 0, 0);
      }
      __builtin_amdgcn_s_setprio(0);
      if (kv == qb_t) {  // diagonal: causal mask (col > row)
#pragma unroll
        for (int c = 0; c < 4; ++c)
#pragma unroll
          for (int r = 0; r < 4; ++r)
            if (c * 16 + lr > wt * 16 + lg * 4 + r) s[c][r] = -1e30f;
      }

      // online softmax; mrow row-uniform, lsum lane-partial
      float rmax[4];
#pragma unroll
      for (int r = 0; r < 4; ++r)
        rmax[r] = fmaxf(fmaxf(s[0][r], s[1][r]), fmaxf(s[2][r], s[3][r]));
#pragma unroll
      for (int mset = 1; mset <= 8; mset <<= 1)
#pragma unroll
        for (int r = 0; r < 4; ++r)
          rmax[r] = fmaxf(rmax[r], __shfl_xor(rmax[r], mset, 64));
      bool need = (rmax[0] > mrow[0] + 8.0f) | (rmax[1] > mrow[1] + 8.0f) |
                  (rmax[2] > mrow[2] + 8.0f) | (rmax[3] > mrow[3] + 8.0f);
      if (__any(need)) {
        float alpha[4];
#pragma unroll
        for (int r = 0; r < 4; ++r) {
          float mn = fmaxf(mrow[r], rmax[r]);
          alpha[r] = __expf(mrow[r] - mn);
          mrow[r] = mn;
          lsum[r] *= alpha[r];
        }
#pragma unroll
        for (int n = 0; n < 4; ++n)
#pragma unroll
          for (int r = 0; r < 4; ++r)
            acc[n][r] *= alpha[r];
      }
#pragma unroll
      for (int c = 0; c < 4; ++c)
#pragma unroll
        for (int r = 0; r < 4; ++r) {
          float pe = __expf(s[c][r] - mrow[r]);
          s[c][r] = pe;
          lsum[r] += pe;
        }

      // P -> bf16 via per-wave LDS round-trip
#pragma unroll
      for (int c = 0; c < 4; ++c)
#pragma unroll
        for (int r = 0; r < 4; ++r)
          p_lds[w][lg * 4 + r][c * 16 + lr] = f2bf(s[c][r]);
      bf16x8 pa0 = __builtin_bit_cast(bf16x8, *(const u32x4*)&p_lds[w][lr][lg * 8]);
      bf16x8 pa1 = __builtin_bit_cast(bf16x8, *(const u32x4*)&p_lds[w][lr][lg * 8 + 32]);

      // PV: B-fragments via hardware transpose reads (immediate offsets)
      {
        u32x2 t[8];
        TRR(t[0], vtr, "0");    TRR(t[1], vtr, "512");
        TRR(t[2], vtr, "4096"); TRR(t[3], vtr, "4608");
        TRR(t[4], vtr, "128");  TRR(t[5], vtr, "640");
        TRR(t[6], vtr, "4224"); TRR(t[7], vtr, "4736");
        asm volatile("s_waitcnt lgkmcnt(0)" ::: "memory");
        __builtin_amdgcn_sched_barrier(0);
        __builtin_amdgcn_s_setprio(1);
#pragma unroll
        for (int n2 = 0; n2 < 2; ++n2) {
          u32x4 vlo, vhi;
          vlo[0] = t[n2 * 4 + 0][0]; vlo[1] = t[n2 * 4 + 0][1];
          vlo[2] = t[n2 * 4 + 1][0]; vlo[3] = t[n2 * 4 + 1][1];
          vhi[0] = t[n2 * 4 + 2][0]; vhi[1] = t[n2 * 4 + 2][1];
          vhi[2] = t[n2 * 4 + 3][0]; vhi[3] = t[n2 * 4 + 3][1];
          acc[n2] = __builtin_amdgcn_mfma_f32_16x16x32_bf16(pa0, __builtin_bit_cast(bf16x8, vlo), acc[n2], 0, 0, 0);
          acc[n2] = __builtin_amdgcn_mfma_f32_16x16x32_bf16(pa1, __builtin_bit_cast(bf16x8, vhi), acc[n2], 0, 0, 0);
        }
        __builtin_amdgcn_s_setprio(0);
      }
      {
        u32x2 t[8];
        TRR(t[0], vtr, "256");  TRR(t[1], vtr, "768");
        TRR(t[2], vtr, "4352"); TRR(t[3], vtr, "4864");
        TRR(t[4], vtr, "384");  TRR(t[5], vtr, "896");
        TRR(t[6], vtr, "4480"); TRR(t[7], vtr, "4992");
        asm volatile("s_waitcnt lgkmcnt(0)" ::: "memory");
        __builtin_amdgcn_sched_barrier(0);
        __builtin_amdgcn_s_setprio(1);
#pragma unroll
        for (int n2 = 0; n2 < 2; ++n2) {
          int n = 2 + n2;
          u32x4 vlo, vhi;
          vlo[0] = t[n2 * 4 + 0][0]; vlo[1] = t[n2 * 4 + 0][1];
          vlo[2] = t[n2 * 4 + 1][0]; vlo[3] = t[n2 * 4 + 1][1];
          vhi[0] = t[n2 * 4 + 2][0]; vhi[1] = t[n2 * 4 + 2][1];
          vhi[2] = t[n2 * 4 + 3][0]; vhi[3] = t[n2 * 4 + 3][1];
          acc[n] = __builtin_amdgcn_mfma_f32_16x16x32_bf16(pa0, __builtin_bit_cast(bf16x8, vlo), acc[n], 0, 0, 0);
          acc[n] = __builtin_amdgcn_mfma_f32_16x16x32_bf16(pa1, __builtin_bit_cast(bf16x8, vhi), acc[n], 0, 0, 0);
        }
        __builtin_amdgcn_s_setprio(0);
      }
    }
  }

  // epilogue: reduce lane-partial sums, normalize, write this wave's tile
#pragma unroll
  for (int mset = 1; mset <= 8; mset <<= 1)
#pragma unroll
    for (int r = 0; r < 4; ++r)
      lsum[r] += __shfl_xor(lsum[r], mset, 64);
#pragma unroll
  for (int n = 0; n < 4; ++n)
#pragma unroll
    for (int r = 0; r < 4; ++r) {
      int t = qb_t * 64 + wt * 16 + lg * 4 + r;
      int dd = n * 16 + lr;
      O[(size_t)(b * TSEQ + t) * DMODEL + h * 64 + dd] = f2bf(acc[n][r] / lsum[r]);
    }
}

extern "C" void kernel_launch(void* const* d_in, const int* in_sizes, int n_in,
                              void* d_out, int out_size, void* d_ws, size_t ws_size,
                              hipStream_t stream) {
  const float* x     = (const float*)d_in[0];
  const float* w_qkv = (const float*)d_in[1];
  const float* w_out = (const float*)d_in[2];
  float* out = (float*)d_out;

  char* ws = (char*)d_ws;
  size_t off = 0;
  auto alloc = [&](size_t bytes) {
    char* p = ws + off;
    off += (bytes + 255) & ~(size_t)255;
    return p;
  };
  const size_t MT = (size_t)BSZ * TSEQ;  // 4096
  u16* xb    = (u16*)alloc(MT * DMODEL * 2);
  u16* wqkvT = (u16*)alloc((size_t)3 * DMODEL * DMODEL * 2);
  u16* woutT = (u16*)alloc((size_t)DMODEL * DMODEL * 2);
  u16* Qh    = (u16*)alloc(MT * DMODEL * 2);
  u16* Kh    = (u16*)alloc(MT * DMODEL * 2);
  u16* Vh    = (u16*)alloc(MT * DMODEL * 2);
  u16* aout  = (u16*)alloc(MT * DMODEL * 2);
  float* cosT = (float*)alloc((size_t)TSEQ * 32 * 4);
  float* sinT = (float*)alloc((size_t)TSEQ * 32 * 4);
  if (ws_size < off) return;

  k_prep<<<3328, 256, 0, stream>>>(x, xb, w_qkv, wqkvT, w_out, woutT, cosT, sinT);
  k_gemm_qkv<<<dim3(24, 32), 256, 0, stream>>>(xb, wqkvT, Qh, Kh, Vh, cosT, sinT);
  k_flash<<<dim3(16, BSZ * NHEAD), 512, 0, stream>>>(Qh, Kh, Vh, aout);
  k_gemm_out<<<dim3(16, 32), 256, 0, stream>>>(aout, woutT, out);
}